// Round 7
// baseline (1432.342 us; speedup 1.0000x reference)
//
#include <hip/hip_runtime.h>
#include <cstdint>

static constexpr int B2 = 2;
static constexpr int C = 512;
static constexpr int N = 4096;
static constexpr long CN = (long)C * N;
static constexpr long NC = (long)N * C;
static constexpr long CC = (long)C * C;
static constexpr long NN = (long)N * N;
static constexpr float EPSC = 1e-5f;
static constexpr int KSEL = 308;       // N - int(N*0.925)
static constexpr int NS_ITERS = 5;

typedef __attribute__((ext_vector_type(8))) __bf16 bf16x8;
typedef __attribute__((ext_vector_type(4))) float f32x4;

__device__ __forceinline__ float wredSum(float v){
#pragma unroll
  for (int o = 32; o >= 1; o >>= 1) v += __shfl_xor(v, o, 64);
  return v;
}

__device__ __forceinline__ void gld16(const __bf16* g, __bf16* l){
  __builtin_amdgcn_global_load_lds(
      (const __attribute__((address_space(1))) void*)g,
      (__attribute__((address_space(3))) void*)l, 16, 0, 0);
}

__device__ __forceinline__ void splitw(float v, __bf16* ph, __bf16* pl, long o){
  __bf16 h = (__bf16)v;
  ph[o] = h;
  pl[o] = (__bf16)(v - (float)h);
}

// ======================= split/plain bf16 MFMA GEMM, 128x128 tile, BK=32 =======================
template<int PASSES, int TMH, int OUTMODE>
__global__ __launch_bounds__(256) void k_mm(
    const __bf16* __restrict__ Ah, const __bf16* __restrict__ Al,
    const __bf16* __restrict__ Bh, const __bf16* __restrict__ Bl,
    float* __restrict__ Cf, __bf16* __restrict__ Coh, __bf16* __restrict__ Col,
    int Nn, int K, long sAz, long sBz, long sCz,
    float alpha, const float* __restrict__ alpha_ptr,
    const float* __restrict__ brow, long sBr,
    const float* __restrict__ bcol, long sBc,
    const float* __restrict__ c0p,
    const float* __restrict__ addsrc, long sAddz)
{
  constexpr int NB = (PASSES == 3) ? 4 : 2;
  constexpr int SB = (PASSES == 3) ? 2 : 1;
  __shared__ __align__(16) __bf16 sm[NB][128 * 32];
  const int z = blockIdx.z;
  const int i0 = blockIdx.x * 128;
  const int j0 = blockIdx.y * 128;
  const int tid = threadIdx.x;
  const int lane = tid & 63;
  const int w = tid >> 6;
  const int wr = (w >> 1) * 64, wc = (w & 1) * 64;
  const int lr = lane & 15;
  const int g = lane >> 4;

  const __bf16* pAh = Ah + (long)z * sAz + (long)i0 * K;
  const __bf16* pBh = Bh + (long)z * sBz + (long)j0 * K;
  const __bf16* pAl = (PASSES == 3) ? (Al + (long)z * sAz + (long)i0 * K) : nullptr;
  const __bf16* pBl = (PASSES == 3) ? (Bl + (long)z * sBz + (long)j0 * K) : nullptr;

  f32x4 acc[4][4] = {};

  for (int kt = 0; kt < K; kt += 32){
#pragma unroll
    for (int p = 0; p < 2; ++p){
      const int t2 = p * 256 + tid;
      const int row = t2 >> 2;
      const int gs = (t2 & 3) ^ ((row >> 1) & 3);
      const long go = (long)row * K + kt + gs * 8;
      gld16(pAh + go, &sm[0][t2 * 8]);
      gld16(pBh + go, &sm[SB][t2 * 8]);
      if constexpr (PASSES == 3){
        gld16(pAl + go, &sm[1][t2 * 8]);
        gld16(pBl + go, &sm[3][t2 * 8]);
      }
    }
    __syncthreads();
    bf16x8 fa[4], fal[4], fb[4], fbl[4];
#pragma unroll
    for (int mi = 0; mi < 4; ++mi){
      const int row = wr + mi * 16 + lr;
      const int off = row * 32 + ((g ^ ((row >> 1) & 3)) * 8);
      fa[mi] = *(const bf16x8*)(&sm[0][off]);
      if constexpr (PASSES == 3) fal[mi] = *(const bf16x8*)(&sm[1][off]);
    }
#pragma unroll
    for (int ni = 0; ni < 4; ++ni){
      const int row = wc + ni * 16 + lr;
      const int off = row * 32 + ((g ^ ((row >> 1) & 3)) * 8);
      fb[ni] = *(const bf16x8*)(&sm[SB][off]);
      if constexpr (PASSES == 3) fbl[ni] = *(const bf16x8*)(&sm[3][off]);
    }
#pragma unroll
    for (int mi = 0; mi < 4; ++mi)
#pragma unroll
      for (int ni = 0; ni < 4; ++ni){
        acc[mi][ni] = __builtin_amdgcn_mfma_f32_16x16x32_bf16(fa[mi], fb[ni], acc[mi][ni], 0, 0, 0);
        if constexpr (PASSES == 3){
          acc[mi][ni] = __builtin_amdgcn_mfma_f32_16x16x32_bf16(fa[mi],  fbl[ni], acc[mi][ni], 0, 0, 0);
          acc[mi][ni] = __builtin_amdgcn_mfma_f32_16x16x32_bf16(fal[mi], fb[ni],  acc[mi][ni], 0, 0, 0);
        }
      }
    __syncthreads();
  }

  float al2 = alpha;
  if (alpha_ptr) al2 *= alpha_ptr[z];
  const float c0v = c0p ? c0p[z] : 0.f;
#pragma unroll
  for (int mi = 0; mi < 4; ++mi){
#pragma unroll
    for (int ni = 0; ni < 4; ++ni){
      const int col = j0 + wc + ni * 16 + lr;
      const float bc = (bcol ? bcol[z * sBc + col] : 0.f) + c0v;
#pragma unroll
      for (int j = 0; j < 4; ++j){
        const int row = i0 + wr + mi * 16 + g * 4 + j;
        float v = acc[mi][ni][j] * al2;
        if (TMH) v = (((row == col) ? 3.f : 0.f) - v) * 0.5f;
        if (brow) v += brow[z * sBr + row];
        v += bc;
        if (addsrc) v += addsrc[(long)z * sAddz + (long)row * Nn + col];
        const long o = (long)z * sCz + (long)row * Nn + col;
        if (OUTMODE == 0){ Cf[o] = v; }
        else if (OUTMODE == 1){ __bf16 h = (__bf16)v; Coh[o] = h; Col[o] = (__bf16)(v - (float)h); }
        else { Coh[o] = (__bf16)v; }
      }
    }
  }
}

// ======================= split-bf16 MFMA GEMM, 64x64 tile, BK=64 (always 3-pass) =======================
template<int TMH, int OUTMODE, int NSYZ>
__global__ __launch_bounds__(256) void k_mm64(
    const __bf16* __restrict__ Ah, const __bf16* __restrict__ Al,
    const __bf16* __restrict__ Bh, const __bf16* __restrict__ Bl,
    const __bf16* __restrict__ tH, const __bf16* __restrict__ tL,
    float* __restrict__ Cf, __bf16* __restrict__ Coh, __bf16* __restrict__ Col,
    int Nn, int K, long sAz, long sBz, long sCz, float alpha)
{
  __shared__ __align__(16) __bf16 sm[4][64 * 64];
  const int z = blockIdx.z;
  const __bf16 *bAh, *bAl, *bBh, *bBl;
  long oC;
  if constexpr (NSYZ){
    if (z < 4){
      bAh = Ah + (long)z * CC; bAl = Al + (long)z * CC;
      bBh = tH + (long)z * CC; bBl = tL + (long)z * CC;
      oC = (long)z * CC;
    } else {
      const int zz = z - 4;
      bAh = tH + (long)zz * CC; bAl = tL + (long)zz * CC;
      bBh = Ah + (long)(4 + zz) * CC; bBl = Al + (long)(4 + zz) * CC;
      oC = (long)(4 + zz) * CC;
    }
  } else {
    bAh = Ah + (long)z * sAz; bAl = Al + (long)z * sAz;
    bBh = Bh + (long)z * sBz; bBl = Bl + (long)z * sBz;
    oC = (long)z * sCz;
  }
  const int i0 = blockIdx.x * 64;
  const int j0 = blockIdx.y * 64;
  const int tid = threadIdx.x;
  const int lane = tid & 63;
  const int w = tid >> 6;
  const int wr = (w >> 1) * 32, wc = (w & 1) * 32;
  const int lr = lane & 15;
  const int g = lane >> 4;

  const __bf16* pAh = bAh + (long)i0 * K;
  const __bf16* pAl = bAl + (long)i0 * K;
  const __bf16* pBh = bBh + (long)j0 * K;
  const __bf16* pBl = bBl + (long)j0 * K;

  f32x4 acc[2][2] = {};

  for (int kt = 0; kt < K; kt += 64){
#pragma unroll
    for (int p = 0; p < 2; ++p){
      const int t2 = p * 256 + tid;
      const int row = t2 >> 3;
      const int gs = (t2 & 7) ^ (row & 7);
      const long go = (long)row * K + kt + gs * 8;
      gld16(pAh + go, &sm[0][t2 * 8]);
      gld16(pAl + go, &sm[1][t2 * 8]);
      gld16(pBh + go, &sm[2][t2 * 8]);
      gld16(pBl + go, &sm[3][t2 * 8]);
    }
    __syncthreads();
#pragma unroll
    for (int ks = 0; ks < 2; ++ks){
      bf16x8 fa[2], fal[2], fb[2], fbl[2];
#pragma unroll
      for (int mi = 0; mi < 2; ++mi){
        const int row = wr + mi * 16 + lr;
        const int off = row * 64 + (((ks * 4 + g) ^ (row & 7)) * 8);
        fa[mi]  = *(const bf16x8*)(&sm[0][off]);
        fal[mi] = *(const bf16x8*)(&sm[1][off]);
      }
#pragma unroll
      for (int ni = 0; ni < 2; ++ni){
        const int row = wc + ni * 16 + lr;
        const int off = row * 64 + (((ks * 4 + g) ^ (row & 7)) * 8);
        fb[ni]  = *(const bf16x8*)(&sm[2][off]);
        fbl[ni] = *(const bf16x8*)(&sm[3][off]);
      }
#pragma unroll
      for (int mi = 0; mi < 2; ++mi)
#pragma unroll
        for (int ni = 0; ni < 2; ++ni){
          acc[mi][ni] = __builtin_amdgcn_mfma_f32_16x16x32_bf16(fa[mi],  fb[ni],  acc[mi][ni], 0, 0, 0);
          acc[mi][ni] = __builtin_amdgcn_mfma_f32_16x16x32_bf16(fa[mi],  fbl[ni], acc[mi][ni], 0, 0, 0);
          acc[mi][ni] = __builtin_amdgcn_mfma_f32_16x16x32_bf16(fal[mi], fb[ni],  acc[mi][ni], 0, 0, 0);
        }
    }
    __syncthreads();
  }

#pragma unroll
  for (int mi = 0; mi < 2; ++mi){
#pragma unroll
    for (int ni = 0; ni < 2; ++ni){
      const int col = j0 + wc + ni * 16 + lr;
#pragma unroll
      for (int j = 0; j < 4; ++j){
        const int row = i0 + wr + mi * 16 + g * 4 + j;
        float v = acc[mi][ni][j] * alpha;
        if (TMH) v = (((row == col) ? 3.f : 0.f) - v) * 0.5f;
        const long o = oC + (long)row * Nn + col;
        if (OUTMODE == 0){ Cf[o] = v; }
        else { __bf16 h = (__bf16)v; Coh[o] = h; Col[o] = (__bf16)(v - (float)h); }
      }
    }
  }
}

// ======================= fused corr+PV: res[n,c] = sum_m corr(E[n,m]) * h[c,m] =======================
// 64 n-rows x 256 c-cols per block (c split halved vs round-6 -> E read/exp halved)
__global__ __launch_bounds__(256) void k_pv(
    const float* __restrict__ E, const __bf16* __restrict__ Bh,
    const float* __restrict__ rm, const float* __restrict__ rsc,
    const float* __restrict__ mxv, const float* __restrict__ myv,
    __bf16* __restrict__ resH)
{
  __shared__ __align__(16) __bf16 sa[64 * 32];
  __shared__ __align__(16) __bf16 sb[256 * 32];
  const int z = blockIdx.z;
  const int n0 = blockIdx.x * 64;
  const int c0 = blockIdx.y * 256;
  const int tid = threadIdx.x;
  const int lane = tid & 63;
  const int w = tid >> 6;
  const int wr = (w >> 1) * 32, wc = (w & 1) * 128;
  const int lr = lane & 15, g = lane >> 4;

  const float* pe = E + (long)z * NN + (long)n0 * N;
  const __bf16* pB = Bh + (long)z * CN + (long)c0 * N;

  const int ar = tid >> 2;
  const int slot = tid & 3;
  const int gv = slot ^ ((ar >> 1) & 3);
  const float rmv = rm[(long)z * N + n0 + ar];
  const float rsv = rsc[(long)z * N + n0 + ar];
  const float tgt = mxv[n0 + ar];

  f32x4 acc[2][8] = {};

  for (int kt = 0; kt < N; kt += 32){
    const float4 e0 = *(const float4*)(pe + (long)ar * N + kt + gv * 8);
    const float4 e1 = *(const float4*)(pe + (long)ar * N + kt + gv * 8 + 4);
    const float4 m0 = *(const float4*)(myv + kt + gv * 8);
    const float4 m1 = *(const float4*)(myv + kt + gv * 8 + 4);
    bf16x8 pk;
    pk[0] = (__bf16)((m0.x == tgt) ? __expf(e0.x - rmv) * rsv : 0.f);
    pk[1] = (__bf16)((m0.y == tgt) ? __expf(e0.y - rmv) * rsv : 0.f);
    pk[2] = (__bf16)((m0.z == tgt) ? __expf(e0.z - rmv) * rsv : 0.f);
    pk[3] = (__bf16)((m0.w == tgt) ? __expf(e0.w - rmv) * rsv : 0.f);
    pk[4] = (__bf16)((m1.x == tgt) ? __expf(e1.x - rmv) * rsv : 0.f);
    pk[5] = (__bf16)((m1.y == tgt) ? __expf(e1.y - rmv) * rsv : 0.f);
    pk[6] = (__bf16)((m1.z == tgt) ? __expf(e1.z - rmv) * rsv : 0.f);
    pk[7] = (__bf16)((m1.w == tgt) ? __expf(e1.w - rmv) * rsv : 0.f);
    *(bf16x8*)(&sa[ar * 32 + slot * 8]) = pk;
#pragma unroll
    for (int p = 0; p < 4; ++p){
      const int t2 = p * 256 + tid;
      const int row = t2 >> 2;
      const int gs = (t2 & 3) ^ ((row >> 1) & 3);
      gld16(pB + (long)row * N + kt + gs * 8, &sb[t2 * 8]);
    }
    __syncthreads();
    bf16x8 fa[2], fb[8];
#pragma unroll
    for (int mi = 0; mi < 2; ++mi){
      const int row = wr + mi * 16 + lr;
      fa[mi] = *(const bf16x8*)(&sa[row * 32 + ((g ^ ((row >> 1) & 3)) * 8)]);
    }
#pragma unroll
    for (int ni = 0; ni < 8; ++ni){
      const int row = wc + ni * 16 + lr;
      fb[ni] = *(const bf16x8*)(&sb[row * 32 + ((g ^ ((row >> 1) & 3)) * 8)]);
    }
#pragma unroll
    for (int mi = 0; mi < 2; ++mi)
#pragma unroll
      for (int ni = 0; ni < 8; ++ni)
        acc[mi][ni] = __builtin_amdgcn_mfma_f32_16x16x32_bf16(fa[mi], fb[ni], acc[mi][ni], 0, 0, 0);
    __syncthreads();
  }
#pragma unroll
  for (int mi = 0; mi < 2; ++mi)
#pragma unroll
    for (int ni = 0; ni < 8; ++ni){
      const int c = c0 + wc + ni * 16 + lr;
#pragma unroll
      for (int j = 0; j < 4; ++j){
        const int n = n0 + wr + mi * 16 + g * 4 + j;
        resH[(long)z * NC + (long)n * C + c] = (__bf16)acc[mi][ni][j];
      }
    }
}

// ======================= small helpers =======================
__global__ __launch_bounds__(256) void k_wtw(const float* __restrict__ A, const float* __restrict__ B,
                                             float* __restrict__ C2, float alpha){
  __shared__ float sa[16][32], sb[16][32];
  const int i0 = blockIdx.x * 32, j0 = blockIdx.y * 32;
  const int t = threadIdx.x;
  const int ti = t & 15, tj = t >> 4;
  const int li = t & 31, lc = t >> 5;
  float acc[2][2] = {};
  for (int cb = 0; cb < C; cb += 16){
    sa[lc][li]     = A[(long)(cb + lc) * C + i0 + li];
    sa[lc + 8][li] = A[(long)(cb + lc + 8) * C + i0 + li];
    sb[lc][li]     = B[(long)(cb + lc) * C + j0 + li];
    sb[lc + 8][li] = B[(long)(cb + lc + 8) * C + j0 + li];
    __syncthreads();
#pragma unroll
    for (int c = 0; c < 16; ++c){
      const float a0 = sa[c][ti * 2], a1 = sa[c][ti * 2 + 1];
      const float b0 = sb[c][tj * 2], b1 = sb[c][tj * 2 + 1];
      acc[0][0] = fmaf(a0, b0, acc[0][0]); acc[0][1] = fmaf(a0, b1, acc[0][1]);
      acc[1][0] = fmaf(a1, b0, acc[1][0]); acc[1][1] = fmaf(a1, b1, acc[1][1]);
    }
    __syncthreads();
  }
#pragma unroll
  for (int r = 0; r < 2; ++r)
#pragma unroll
    for (int s = 0; s < 2; ++s)
      C2[(long)(i0 + ti * 2 + r) * C + j0 + tj * 2 + s] = acc[r][s] * alpha;
}

__global__ __launch_bounds__(256) void k_wtv(const float* __restrict__ W, const float* __restrict__ b,
                                             float* __restrict__ u){
  __shared__ float sb2[C];
  const int t = threadIdx.x;
  sb2[t] = b[t]; sb2[t + 256] = b[t + 256];
  __syncthreads();
  const int e = blockIdx.x * 256 + t;
  float acc = 0.f;
  for (int c = 0; c < C; ++c) acc = fmaf(W[(long)c * C + e], sb2[c], acc);
  u[e] = acc;
}

__global__ void k_dot2(const float* __restrict__ a1, const float* __restrict__ b1,
                       const float* __restrict__ a2, const float* __restrict__ b2,
                       float* __restrict__ c0m2, float* __restrict__ c0s4){
  const int t = threadIdx.x;
  float s1 = 0.f, s2 = 0.f;
  for (int i = t; i < C; i += 256){ s1 += a1[i] * b1[i]; s2 += a2[i] * b2[i]; }
  __shared__ float sh1[4], sh2[4];
  s1 = wredSum(s1); s2 = wredSum(s2);
  if ((t & 63) == 0){ sh1[t >> 6] = s1; sh2[t >> 6] = s2; }
  __syncthreads();
  if (t == 0){
    float d1 = sh1[0] + sh1[1] + sh1[2] + sh1[3];
    float d2 = sh2[0] + sh2[1] + sh2[2] + sh2[3];
    c0m2[0] = d1; c0m2[1] = d1;
    c0s4[0] = d2; c0s4[1] = d2; c0s4[2] = d2; c0s4[3] = d2;
  }
}

__global__ __launch_bounds__(256) void k_pixvec(const __bf16* __restrict__ X, const float* __restrict__ u,
                                                float* __restrict__ out){
  const int z = blockIdx.y;
  const int wv = threadIdx.x >> 6, lane = threadIdx.x & 63;
  const int n = blockIdx.x * 4 + wv;
  float acc = 0.f;
  for (int d = lane; d < C; d += 64) acc += (float)X[(long)z * NC + (long)n * C + d] * u[d];
  acc = wredSum(acc);
  if (lane == 0) out[(long)z * N + n] = acc;
}

// ======================= prep / stats =======================
__global__ __launch_bounds__(256) void k_stats(const float* __restrict__ x, const float* __restrict__ y,
                                               float* __restrict__ meanv, float* __restrict__ invs){
  const int bid = blockIdx.x;
  const int t = bid >> 9, c = bid & 511;
  const float* src = (t < 2 ? x : y) + (long)(t & 1) * CN + (long)c * N;
  const int tid = threadIdx.x;
  float s1 = 0.f, s2 = 0.f;
  for (int i = tid; i < N; i += 256){ float v = src[i]; s1 += v; s2 += v * v; }
  __shared__ float sh1[4], sh2[4];
  s1 = wredSum(s1); s2 = wredSum(s2);
  if ((tid & 63) == 0){ sh1[tid >> 6] = s1; sh2[tid >> 6] = s2; }
  __syncthreads();
  if (tid == 0){
    float m = (sh1[0] + sh1[1] + sh1[2] + sh1[3]) * (1.f / (float)N);
    float ex2 = (sh2[0] + sh2[1] + sh2[2] + sh2[3]) * (1.f / (float)N);
    float var = ex2 - m * m;
    meanv[t * C + c] = m;
    invs[t * C + c] = rsqrtf((var > 0.f ? var : 0.f) + EPSC);
  }
}

__global__ __launch_bounds__(256) void k_prep(const float* __restrict__ src,
                                              const float* __restrict__ meanv, const float* __restrict__ invs, int toff,
                                              __bf16* __restrict__ adH,
                                              __bf16* __restrict__ fcH, __bf16* __restrict__ fcL,
                                              __bf16* __restrict__ ccH, __bf16* __restrict__ ccL,
                                              __bf16* __restrict__ rwH){
  __shared__ float tile[64][65];
  const int z = blockIdx.z;
  const int n0 = blockIdx.x * 64;
  const int c0 = blockIdx.y * 64;
  const int tid = threadIdx.x;
  const int tx = tid & 63, ty = tid >> 6;
  const int tgt = toff + z;
#pragma unroll
  for (int it = 0; it < 16; ++it){
    const int cc = it * 4 + ty;
    const float v = src[(long)z * CN + (long)(c0 + cc) * N + n0 + tx];
    tile[cc][tx] = v;
    const float cen = v - meanv[tgt * C + c0 + cc];
    splitw(cen, ccH, ccL, (long)tgt * CN + (long)(c0 + cc) * N + n0 + tx);
  }
  __syncthreads();
  const float m = meanv[tgt * C + c0 + tx];
  const float r = invs[tgt * C + c0 + tx];
#pragma unroll
  for (int it = 0; it < 16; ++it){
    const int p = it * 4 + ty;
    const float v = tile[tx][p];
    const float cen = v - m;
    const long o = (long)z * NC + (long)(n0 + p) * C + c0 + tx;
    adH[o] = (__bf16)(cen * r);
    splitw(cen, fcH, fcL, (long)tgt * NC + (long)(n0 + p) * C + c0 + tx);
    if (rwH) rwH[o] = (__bf16)v;
  }
}

__global__ __launch_bounds__(256) void k_wcvt(const float* __restrict__ s, __bf16* __restrict__ h,
                                              __bf16* __restrict__ l, int n){
  int i = blockIdx.x * 256 + threadIdx.x;
  if (i < n) splitw(s[i], h, l, i);
}
__global__ __launch_bounds__(256) void k_wcvt_h(const float* __restrict__ s, __bf16* __restrict__ h, int n){
  int i = blockIdx.x * 256 + threadIdx.x;
  if (i < n) h[i] = (__bf16)s[i];
}

// ======================= cov diag / power iteration / NS init =======================
__global__ void k_diag(float* __restrict__ cov){
  const int z = blockIdx.x, t = threadIdx.x;
  for (int i = t; i < C; i += 256) cov[(long)z * CC + (long)i * C + i] += 2.f * EPSC;
}

__global__ __launch_bounds__(256) void k_powit(const float* __restrict__ cov,
                                               float* __restrict__ invt, float* __restrict__ invsqt){
  __shared__ float v[C], red[4];
  const int z = blockIdx.x, t = threadIdx.x;
  const float* A = cov + (long)z * CC;
  const int j0 = t, j1 = t + 256;
  v[j0] = 1.f + 0.0003f * (float)j0;
  v[j1] = 1.f + 0.0003f * (float)j1;
  __syncthreads();
  float lam = 1.f;
  for (int it = 0; it < 8; ++it){
    float w0a = 0.f, w0b = 0.f, w1a = 0.f, w1b = 0.f;
#pragma unroll 4
    for (int c = 0; c < C; c += 2){
      const float vc0 = v[c], vc1 = v[c + 1];
      w0a = fmaf(A[(long)c * C + j0], vc0, w0a);
      w1a = fmaf(A[(long)c * C + j1], vc0, w1a);
      w0b = fmaf(A[(long)(c + 1) * C + j0], vc1, w0b);
      w1b = fmaf(A[(long)(c + 1) * C + j1], vc1, w1b);
    }
    const float w0 = w0a + w0b, w1 = w1a + w1b;
    float s = w0 * w0 + w1 * w1;
    s = wredSum(s);
    if ((t & 63) == 0) red[t >> 6] = s;
    __syncthreads();
    const float nrm = sqrtf(red[0] + red[1] + red[2] + red[3]);
    lam = nrm;
    const float inv = 1.f / nrm;
    v[j0] = w0 * inv;
    v[j1] = w1 * inv;
    __syncthreads();
  }
  if (t == 0){
    const float tt = 1.02f * lam;
    invt[z] = 1.f / tt;
    invsqt[z] = rsqrtf(tt);
  }
}

__global__ __launch_bounds__(256) void k_ns_init(const float* __restrict__ cov, const float* __restrict__ invt,
                                                 __bf16* __restrict__ h, __bf16* __restrict__ l,
                                                 __bf16* __restrict__ cph, __bf16* __restrict__ cpl){
  const int r = blockIdx.x, z = blockIdx.y;
  const long base = (long)z * CC + (long)r * C;
  const float it = invt[z];
  for (int i = threadIdx.x; i < C; i += 256){
    const float v = cov[base + i] * it;
    splitw(v, h, l, base + i);
    splitw(v, cph, cpl, base + i);
    h[4 * CC + base + i] = (__bf16)((i == r) ? 1.f : 0.f);
    l[4 * CC + base + i] = (__bf16)0.f;
  }
}

// ======================= fused online row-softmax + column accumulation (self path) =======================
// grid (N/16); block handles 16 rows: phase A online (m,S) per row; phase B column partials.
__global__ __launch_bounds__(256) void k_rowcol(const float* __restrict__ E, float* __restrict__ partials){
  __shared__ float srm[16], srs[16];
  const int blk = blockIdx.x;
  const int r0 = blk * 16;
  const int tid = threadIdx.x;
  const int rr = tid >> 4;
  const int l16 = tid & 15;
  const float* pe = E + (long)(r0 + rr) * N;
  float m = -3.4e38f, s = 0.f;
  for (int i = l16 * 4; i < N; i += 64){
    const float4 v = *(const float4*)(pe + i);
    const float mv = fmaxf(fmaxf(v.x, v.y), fmaxf(v.z, v.w));
    if (mv > m){ s *= __expf(m - mv); m = mv; }
    s += __expf(v.x - m) + __expf(v.y - m) + __expf(v.z - m) + __expf(v.w - m);
  }
#pragma unroll
  for (int o = 8; o >= 1; o >>= 1){
    const float mo = __shfl_xor(m, o, 64);
    const float so = __shfl_xor(s, o, 64);
    const float nm = fmaxf(m, mo);
    s = s * __expf(m - nm) + so * __expf(mo - nm);
    m = nm;
  }
  if (l16 == 0){ srm[rr] = m; srs[rr] = 1.f / s; }
  __syncthreads();
  for (int j = tid * 4; j < N; j += 1024){
    float4 acc = {0.f, 0.f, 0.f, 0.f};
#pragma unroll
    for (int r = 0; r < 16; ++r){
      const float4 e4 = *(const float4*)(E + (long)(r0 + r) * N + j);
      const float rmv = srm[r], rsv = srs[r];
      acc.x += __expf(e4.x - rmv) * rsv;
      acc.y += __expf(e4.y - rmv) * rsv;
      acc.z += __expf(e4.z - rmv) * rsv;
      acc.w += __expf(e4.w - rmv) * rsv;
    }
    *(float4*)(partials + (long)blk * N + j) = acc;
  }
}

__global__ __launch_bounds__(256) void k_colreduce(const float* __restrict__ partials, float* __restrict__ att){
  const int j = blockIdx.x * 256 + threadIdx.x;
  float s = 0.f;
  for (int p = 0; p < 256; ++p) s += partials[(long)p * N + j];
  att[j] = s * (1.f / (float)N);
}

// ======================= main-path masked row stats, single-pass online =======================
// grid (N/16, B2); writes rowmax/rowscale to global for k_pv.
__global__ __launch_bounds__(256) void k_rowstats1(
    const float* __restrict__ E, const float* __restrict__ mx, const float* __restrict__ my,
    float* __restrict__ rowmax, float* __restrict__ rowscale)
{
  const int zz = blockIdx.y;
  const int r0 = blockIdx.x * 16;
  const int tid = threadIdx.x;
  const int rr = tid >> 4;
  const int l16 = tid & 15;
  const int row = r0 + rr;
  const float* pe = E + (long)zz * NN + (long)row * N;
  const float target = mx[row];
  float m = -3.4e38f, s = 0.f, sm = 0.f;
  for (int i = l16 * 4; i < N; i += 64){
    const float4 v = *(const float4*)(pe + i);
    const float4 wv = *(const float4*)(my + i);
    const float mv = fmaxf(fmaxf(v.x, v.y), fmaxf(v.z, v.w));
    if (mv > m){ const float sc = __expf(m - mv); s *= sc; sm *= sc; m = mv; }
    const float e0 = __expf(v.x - m), e1 = __expf(v.y - m);
    const float e2 = __expf(v.z - m), e3 = __expf(v.w - m);
    s += (e0 + e1) + (e2 + e3);
    if (wv.x == target) sm += e0;
    if (wv.y == target) sm += e1;
    if (wv.z == target) sm += e2;
    if (wv.w == target) sm += e3;
  }
#pragma unroll
  for (int o = 8; o >= 1; o >>= 1){
    const float mo = __shfl_xor(m, o, 64);
    const float so = __shfl_xor(s, o, 64);
    const float smo = __shfl_xor(sm, o, 64);
    const float nm = fmaxf(m, mo);
    const float sc0 = __expf(m - nm), sc1 = __expf(mo - nm);
    s = s * sc0 + so * sc1;
    sm = sm * sc0 + smo * sc1;
    m = nm;
  }
  if (l16 == 0){
    float l1 = sm / s;
    if (l1 < 1e-12f) l1 = 1e-12f;
    rowscale[(long)zz * N + row] = 1.f / (s * l1);
    rowmax[(long)zz * N + row] = m;
  }
}

// ======================= mask (radix select) =======================
__global__ __launch_bounds__(256) void k_radix(const float* __restrict__ a, float* __restrict__ thr){
  __shared__ unsigned int vals[N];
  __shared__ float shc[4];
  __shared__ unsigned int p_sh;
  __shared__ int k_sh;
  const float* pa = a + (long)blockIdx.x * N;
  const int tid = threadIdx.x;
  for (int i = tid; i < N; i += 256) vals[i] = __float_as_uint(pa[i]);
  if (tid == 0){ p_sh = 0u; k_sh = KSEL; }
  __syncthreads();
  for (int b = 31; b >= 0; --b){
    const unsigned int bit = 1u << b;
    const unsigned int above = (b == 31) ? 0u : ~((bit << 1) - 1u);
    const unsigned int p = p_sh;
    int cnt = 0;
    for (int i = tid; i < N; i += 256){
      unsigned int v = vals[i];
      if ((v & above) == p && (v & bit)) cnt++;
    }
    float cf = wredSum((float)cnt);
    if ((tid & 63) == 0) shc[tid >> 6] = cf;
    __syncthreads();
    if (tid == 0){
      int c1 = (int)(shc[0] + shc[1] + shc[2] + shc[3] + 0.5f);
      if (k_sh <= c1) p_sh = p | bit;
      else k_sh -= c1;
    }
    __syncthreads();
  }
  if (tid == 0) thr[blockIdx.x] = __uint_as_float(p_sh);
}

__global__ __launch_bounds__(256) void k_mask(const float* __restrict__ ax, const float* __restrict__ ay,
                                              const float* __restrict__ thr, float* __restrict__ mx,
                                              float* __restrict__ my){
  int j = blockIdx.x * 256 + threadIdx.x;
  mx[j] = (ax[j] >= thr[0] && ax[N + j] >= thr[1]) ? 1.f : 0.f;
  my[j] = (ay[j] >= thr[2] && ay[N + j] >= thr[3]) ? 1.f : 0.f;
}

// ======================= host =======================
extern "C" void kernel_launch(void* const* d_in, const int* in_sizes, int n_in,
                              void* d_out, int out_size, void* d_ws, size_t ws_size,
                              hipStream_t stream)
{
  const float* x     = (const float*)d_in[0];
  const float* y     = (const float*)d_in[1];
  const float* f_w   = (const float*)d_in[2];
  const float* f_b   = (const float*)d_in[3];
  const float* g_w   = (const float*)d_in[4];
  const float* g_b   = (const float*)d_in[5];
  const float* saf_w = (const float*)d_in[6];
  const float* saf_b = (const float*)d_in[7];
  const float* sag_w = (const float*)d_in[8];
  const float* sag_b = (const float*)d_in[9];
  const float* h_w   = (const float*)d_in[10];
  const float* h_b   = (const float*)d_in[11];
  const float* ow    = (const float*)d_in[12];
  const float* ob    = (const float*)d_in[13];

  const size_t MBy = 1ull << 20;
  char* base = (char*)d_ws;
  if (ws_size < 205 * MBy) return;
  auto F  = [&](size_t off){ return (float*)(base + off); };
  auto Bp = [&](size_t off){ return (__bf16*)(base + off); };

  // ---- E region [0,128MB): main-phase energy z=0 at [0,64), z=1 at [64,128)
  float *E0 = F(0);
  __bf16 *ccH = Bp(0), *ccL = Bp(16*MBy);            // [4][C][N] pairs, dies @cov
  float  *covb = F(32*MBy);                          // [4][C][C]
  __bf16 *zpolH = Bp(36*MBy), *zpolL = Bp(38*MBy);   // [4][C][C] pairs
  __bf16 *covPH = Bp(40*MBy), *covPL = Bp(42*MBy);
  float  *KsTf = F(44*MBy), *K2tf = F(45*MBy);
  __bf16 *KsTH = Bp(46*MBy), *KsTL = Bp(46*MBy + 512*1024);
  __bf16 *K2tH = Bp(47*MBy), *hwH = Bp(47*MBy + 512*1024);
  __bf16 *tpH = Bp(48*MBy), *tpL = Bp(50*MBy);       // NS T scratch
  __bf16 *xaH = Bp(64*MBy);                          // dies @zca write
  __bf16 *xzH = Bp(64*MBy), *xzL = Bp(80*MBy);       // [4][N][C] pairs
  __bf16 *ypmH = Bp(96*MBy);                         // dies @hconv
  __bf16 *AsH = Bp(96*MBy), *AsL = Bp(112*MBy);      // [4][N][C] pairs
  // [128,160): fc pairs (die @zca apply) -> resH afterwards (outside E)
  __bf16 *fcH = Bp(128*MBy), *fcL = Bp(144*MBy);
  __bf16 *resH = Bp(128*MBy);                        // [2][N][C]
  // [160,176): NS ping-pong [Y(0-3)|Z(4-7)] pairs
  __bf16 *nsAh = Bp(160*MBy), *nsAl = Bp(164*MBy);
  __bf16 *nsBh = Bp(168*MBy), *nsBl = Bp(172*MBy);
  // [176,205): persistent
  __bf16 *A2H = Bp(176*MBy);
  __bf16 *yaH = Bp(184*MBy);
  __bf16 *hH  = Bp(192*MBy);
  __bf16 *owH = Bp(200*MBy);                         // [200, 200.5)
  size_t so = 200 * MBy + 512 * 1024;                // smalls [200.5, 201)
  auto SF = [&](size_t bytes){ float* p = F(so); so += bytes; return p; };
  float *meanv = SF(8*1024), *invs = SF(8*1024);
  float *rm = SF(32*1024), *rsc = SF(32*1024);
  float *mxv = SF(16*1024), *myv = SF(16*1024);
  float *rvec2 = SF(32*1024), *cvec2 = SF(32*1024);
  float *rvS = SF(64*1024), *cvS = SF(64*1024);
  float *u1m = SF(2*1024), *u2m = SF(2*1024), *u1s = SF(2*1024), *u2s = SF(2*1024);
  float *c0m2 = SF(64), *c0s4 = SF(64), *thr = SF(64);
  float *invt = SF(64), *invsqt = SF(64);
  float *partials = F(201*MBy);                      // [256][N] f32 = 4MB, [201,205)

  float* outm = (float*)d_out;               // [2][C][N]
  float* attx = outm + B2 * CN;              // [2][N]
  float* atty = attx + (long)B2 * N;

  // 1) stats + prep
  k_stats<<<dim3(4 * C), dim3(256), 0, stream>>>(x, y, meanv, invs);
  k_prep<<<dim3(64, 8, 2), dim3(256), 0, stream>>>(x, meanv, invs, 0, xaH, fcH, fcL, ccH, ccL, nullptr);
  k_prep<<<dim3(64, 8, 2), dim3(256), 0, stream>>>(y, meanv, invs, 2, yaH, fcH, fcL, ccH, ccL, ypmH);

  // 2) weight products & conversions
  k_wtw<<<dim3(16, 16), dim3(256), 0, stream>>>(sag_w, saf_w, KsTf, 1.f);
  k_wtw<<<dim3(16, 16), dim3(256), 0, stream>>>(g_w, f_w, K2tf, 1.f);
  {
    const int nb = (int)(CC / 256);
    k_wcvt<<<nb, 256, 0, stream>>>(KsTf, KsTH, KsTL, (int)CC);
    k_wcvt_h<<<nb, 256, 0, stream>>>(K2tf, K2tH, (int)CC);
    k_wcvt_h<<<nb, 256, 0, stream>>>(h_w, hwH, (int)CC);
    k_wcvt_h<<<nb, 256, 0, stream>>>(ow, owH, (int)CC);
  }
  k_wtv<<<dim3(2), dim3(256), 0, stream>>>(g_w, f_b, u1m);
  k_wtv<<<dim3(2), dim3(256), 0, stream>>>(f_w, g_b, u2m);
  k_wtv<<<dim3(2), dim3(256), 0, stream>>>(sag_w, saf_b, u1s);
  k_wtv<<<dim3(2), dim3(256), 0, stream>>>(saf_w, sag_b, u2s);
  k_dot2<<<dim3(1), dim3(256), 0, stream>>>(f_b, g_b, saf_b, sag_b, c0m2, c0s4);
  k_pixvec<<<dim3(N / 4, 2), dim3(256), 0, stream>>>(xaH, u2m, rvec2);
  k_pixvec<<<dim3(N / 4, 2), dim3(256), 0, stream>>>(yaH, u1m, cvec2);

  // 3) cov + 2eps*I + power-iteration lambda_max
  k_mm64<0,0,0><<<dim3(8, 8, 4), dim3(256), 0, stream>>>(
      ccH, ccL, ccH, ccL, nullptr, nullptr, covb, nullptr, nullptr, C, N, CN, CN, CC, 1.f / (float)(N - 1));
  k_diag<<<dim3(4), dim3(256), 0, stream>>>(covb);
  k_powit<<<dim3(4), dim3(256), 0, stream>>>(covb, invt, invsqt);

  // 4) A2 = xa . K2^T, h conv
  k_mm<1,0,2><<<dim3(32, 4, 2), dim3(256), 0, stream>>>(xaH, nullptr, K2tH, nullptr, nullptr, A2H, nullptr,
      C, C, NC, 0, NC, 1.f, nullptr, nullptr, 0, nullptr, 0, nullptr, nullptr, 0);
  k_mm<1,0,2><<<dim3(4, 32, 2), dim3(256), 0, stream>>>(hwH, nullptr, ypmH, nullptr, nullptr, hH, nullptr,
      N, C, 0, NC, CN, 1.f, nullptr, h_b, 0, nullptr, 0, nullptr, nullptr, 0);

  // 5) Newton-Schulz (5 iters) + split-bf16 polish
  k_ns_init<<<dim3(C, 4), dim3(256), 0, stream>>>(covb, invt, nsAh, nsAl, covPH, covPL);
  __bf16 *cah = nsAh, *cal = nsAl, *cbh = nsBh, *cbl = nsBl;
  for (int it = 0; it < NS_ITERS; ++it){
    k_mm64<1,1,0><<<dim3(8, 8, 4), dim3(256), 0, stream>>>(
        cah + 4*CC, cal + 4*CC, cah, cal, nullptr, nullptr, nullptr, tpH, tpL, C, C, CC, CC, CC, 1.f);
    k_mm64<0,1,1><<<dim3(8, 8, 8), dim3(256), 0, stream>>>(
        cah, cal, nullptr, nullptr, tpH, tpL, nullptr, cbh, cbl, C, C, CC, CC, CC, 1.f);
    __bf16* t;
    t = cah; cah = cbh; cbh = t;
    t = cal; cal = cbl; cbl = t;
  }
  k_mm64<0,1,0><<<dim3(8, 8, 4), dim3(256), 0, stream>>>(
      cah + 4*CC, cal + 4*CC, cah + 4*CC, cal + 4*CC, nullptr, nullptr, nullptr, tpH, tpL, C, C, CC, CC, CC, 1.f);
  k_mm64<1,1,0><<<dim3(8, 8, 4), dim3(256), 0, stream>>>(
      covPH, covPL, tpH, tpL, nullptr, nullptr, nullptr, cbh, cbl, C, C, CC, CC, CC, 1.f);
  k_mm64<0,1,0><<<dim3(8, 8, 4), dim3(256), 0, stream>>>(
      cah + 4*CC, cal + 4*CC, cbh, cbl, nullptr, nullptr, nullptr, zpolH, zpolL, C, C, CC, CC, CC, 1.f);

  // 6) zca apply: xz = invsqt * fc . Z
  k_mm<3,0,1><<<dim3(32, 4, 4), dim3(256), 0, stream>>>(fcH, fcL, zpolH, zpolL, nullptr, xzH, xzL,
      C, C, NC, CC, NC, 1.f, invsqt, nullptr, 0, nullptr, 0, nullptr, nullptr, 0);

  // 6.5) self bias vecs + As = xz . Ks^T
  k_pixvec<<<dim3(N / 4, 4), dim3(256), 0, stream>>>(xzH, u2s, rvS);
  k_pixvec<<<dim3(N / 4, 4), dim3(256), 0, stream>>>(xzH, u1s, cvS);
  k_mm<3,0,1><<<dim3(32, 4, 4), dim3(256), 0, stream>>>(xzH, xzL, KsTH, KsTL, nullptr, AsH, AsL,
      C, C, NC, 0, NC, 1.f, nullptr, nullptr, 0, nullptr, 0, nullptr, nullptr, 0);

  // 7) self-attention energies -> atten (fused rowcol + reduce)
  for (int z = 0; z < 4; ++z){
    k_mm<3,0,0><<<dim3(32, 32, 1), dim3(256), 0, stream>>>(AsH + (long)z*NC, AsL + (long)z*NC,
        xzH + (long)z*NC, xzL + (long)z*NC, E0, nullptr, nullptr,
        N, C, 0, 0, 0, 1.f, nullptr, rvS + (long)z*N, 0, cvS + (long)z*N, 0, c0s4, nullptr, 0);
    k_rowcol<<<dim3(N / 16), dim3(256), 0, stream>>>(E0, partials);
    k_colreduce<<<dim3(16), dim3(256), 0, stream>>>(partials, (z < 2 ? attx : atty) + (long)(z & 1) * N);
  }

  // 8) masks
  k_radix<<<dim3(2), dim3(256), 0, stream>>>(attx, thr);
  k_radix<<<dim3(2), dim3(256), 0, stream>>>(atty, thr + 2);
  k_mask<<<dim3(16), dim3(256), 0, stream>>>(attx, atty, thr, mxv, myv);

  // 9) main path: energy(z=2) -> online masked rowstats -> fused corr+PV -> out conv
  k_mm<1,0,0><<<dim3(32, 32, 2), dim3(256), 0, stream>>>(A2H, nullptr, yaH, nullptr, E0, nullptr, nullptr,
      N, C, NC, NC, NN, 1.f, nullptr, rvec2, N, cvec2, N, c0m2, nullptr, 0);
  k_rowstats1<<<dim3(N / 16, 2), dim3(256), 0, stream>>>(E0, mxv, myv, rm, rsc);
  k_pv<<<dim3(64, 2, 2), dim3(256), 0, stream>>>(E0, hH, rm, rsc, mxv, myv, resH);
  k_mm<1,0,0><<<dim3(4, 32, 2), dim3(256), 0, stream>>>(owH, nullptr, resH, nullptr, outm, nullptr, nullptr,
      N, C, 0, NC, CN, 1.f, nullptr, ob, 0, nullptr, 0, nullptr, x, CN);
}

// Round 8
// 1368.216 us; speedup vs baseline: 1.0469x; 1.0469x over previous
//
#include <hip/hip_runtime.h>
#include <cstdint>

static constexpr int B2 = 2;
static constexpr int C = 512;
static constexpr int N = 4096;
static constexpr long CN = (long)C * N;
static constexpr long NC = (long)N * C;
static constexpr long CC = (long)C * C;
static constexpr long NN = (long)N * N;
static constexpr float EPSC = 1e-5f;
static constexpr int KSEL = 308;       // N - int(N*0.925)
static constexpr int NS_ITERS = 5;

typedef __attribute__((ext_vector_type(8))) __bf16 bf16x8;
typedef __attribute__((ext_vector_type(4))) float f32x4;

__device__ __forceinline__ float wredSum(float v){
#pragma unroll
  for (int o = 32; o >= 1; o >>= 1) v += __shfl_xor(v, o, 64);
  return v;
}

__device__ __forceinline__ void gld16(const __bf16* g, __bf16* l){
  __builtin_amdgcn_global_load_lds(
      (const __attribute__((address_space(1))) void*)g,
      (__attribute__((address_space(3))) void*)l, 16, 0, 0);
}

__device__ __forceinline__ void splitw(float v, __bf16* ph, __bf16* pl, long o){
  __bf16 h = (__bf16)v;
  ph[o] = h;
  pl[o] = (__bf16)(v - (float)h);
}

// ======================= split/plain bf16 MFMA GEMM, 128x128 tile, BK=32 =======================
// XCD-aware block swizzle (bijective when nwg%8==0; all launches satisfy this).
template<int PASSES, int TMH, int OUTMODE>
__global__ __launch_bounds__(256) void k_mm(
    const __bf16* __restrict__ Ah, const __bf16* __restrict__ Al,
    const __bf16* __restrict__ Bh, const __bf16* __restrict__ Bl,
    float* __restrict__ Cf, __bf16* __restrict__ Coh, __bf16* __restrict__ Col,
    int Nn, int K, long sAz, long sBz, long sCz,
    float alpha, const float* __restrict__ alpha_ptr,
    const float* __restrict__ brow, long sBr,
    const float* __restrict__ bcol, long sBc,
    const float* __restrict__ c0p,
    const float* __restrict__ addsrc, long sAddz)
{
  constexpr int NB = (PASSES == 3) ? 4 : 2;
  constexpr int SB = (PASSES == 3) ? 2 : 1;
  __shared__ __align__(16) __bf16 sm[NB][128 * 32];
  const int z = blockIdx.z;
  const int nwx = gridDim.x;
  int lin = blockIdx.y * nwx + blockIdx.x;
  const int nwg = nwx * gridDim.y;
  if ((nwg & 7) == 0){
    const int cpx = nwg >> 3;
    lin = (lin & 7) * cpx + (lin >> 3);
  }
  const int i0 = (lin % nwx) * 128;
  const int j0 = (lin / nwx) * 128;
  const int tid = threadIdx.x;
  const int lane = tid & 63;
  const int w = tid >> 6;
  const int wr = (w >> 1) * 64, wc = (w & 1) * 64;
  const int lr = lane & 15;
  const int g = lane >> 4;

  const __bf16* pAh = Ah + (long)z * sAz + (long)i0 * K;
  const __bf16* pBh = Bh + (long)z * sBz + (long)j0 * K;
  const __bf16* pAl = (PASSES == 3) ? (Al + (long)z * sAz + (long)i0 * K) : nullptr;
  const __bf16* pBl = (PASSES == 3) ? (Bl + (long)z * sBz + (long)j0 * K) : nullptr;

  f32x4 acc[4][4] = {};

  for (int kt = 0; kt < K; kt += 32){
#pragma unroll
    for (int p = 0; p < 2; ++p){
      const int t2 = p * 256 + tid;
      const int row = t2 >> 2;
      const int gs = (t2 & 3) ^ ((row >> 1) & 3);
      const long go = (long)row * K + kt + gs * 8;
      gld16(pAh + go, &sm[0][t2 * 8]);
      gld16(pBh + go, &sm[SB][t2 * 8]);
      if constexpr (PASSES == 3){
        gld16(pAl + go, &sm[1][t2 * 8]);
        gld16(pBl + go, &sm[3][t2 * 8]);
      }
    }
    __syncthreads();
    bf16x8 fa[4], fal[4], fb[4], fbl[4];
#pragma unroll
    for (int mi = 0; mi < 4; ++mi){
      const int row = wr + mi * 16 + lr;
      const int off = row * 32 + ((g ^ ((row >> 1) & 3)) * 8);
      fa[mi] = *(const bf16x8*)(&sm[0][off]);
      if constexpr (PASSES == 3) fal[mi] = *(const bf16x8*)(&sm[1][off]);
    }
#pragma unroll
    for (int ni = 0; ni < 4; ++ni){
      const int row = wc + ni * 16 + lr;
      const int off = row * 32 + ((g ^ ((row >> 1) & 3)) * 8);
      fb[ni] = *(const bf16x8*)(&sm[SB][off]);
      if constexpr (PASSES == 3) fbl[ni] = *(const bf16x8*)(&sm[3][off]);
    }
#pragma unroll
    for (int mi = 0; mi < 4; ++mi)
#pragma unroll
      for (int ni = 0; ni < 4; ++ni){
        acc[mi][ni] = __builtin_amdgcn_mfma_f32_16x16x32_bf16(fa[mi], fb[ni], acc[mi][ni], 0, 0, 0);
        if constexpr (PASSES == 3){
          acc[mi][ni] = __builtin_amdgcn_mfma_f32_16x16x32_bf16(fa[mi],  fbl[ni], acc[mi][ni], 0, 0, 0);
          acc[mi][ni] = __builtin_amdgcn_mfma_f32_16x16x32_bf16(fal[mi], fb[ni],  acc[mi][ni], 0, 0, 0);
        }
      }
    __syncthreads();
  }

  float al2 = alpha;
  if (alpha_ptr) al2 *= alpha_ptr[z];
  const float c0v = c0p ? c0p[z] : 0.f;
#pragma unroll
  for (int mi = 0; mi < 4; ++mi){
#pragma unroll
    for (int ni = 0; ni < 4; ++ni){
      const int col = j0 + wc + ni * 16 + lr;
      const float bc = (bcol ? bcol[z * sBc + col] : 0.f) + c0v;
#pragma unroll
      for (int j = 0; j < 4; ++j){
        const int row = i0 + wr + mi * 16 + g * 4 + j;
        float v = acc[mi][ni][j] * al2;
        if (TMH) v = (((row == col) ? 3.f : 0.f) - v) * 0.5f;
        if (brow) v += brow[z * sBr + row];
        v += bc;
        if (addsrc) v += addsrc[(long)z * sAddz + (long)row * Nn + col];
        const long o = (long)z * sCz + (long)row * Nn + col;
        if (OUTMODE == 0){ Cf[o] = v; }
        else if (OUTMODE == 1){ __bf16 h = (__bf16)v; Coh[o] = h; Col[o] = (__bf16)(v - (float)h); }
        else { Coh[o] = (__bf16)v; }
      }
    }
  }
}

// ======================= split-bf16 MFMA GEMM, 64x64 tile, BK=64 (always 3-pass) =======================
template<int TMH, int OUTMODE, int NSYZ>
__global__ __launch_bounds__(256) void k_mm64(
    const __bf16* __restrict__ Ah, const __bf16* __restrict__ Al,
    const __bf16* __restrict__ Bh, const __bf16* __restrict__ Bl,
    const __bf16* __restrict__ tH, const __bf16* __restrict__ tL,
    float* __restrict__ Cf, __bf16* __restrict__ Coh, __bf16* __restrict__ Col,
    int Nn, int K, long sAz, long sBz, long sCz, float alpha)
{
  __shared__ __align__(16) __bf16 sm[4][64 * 64];
  const int z = blockIdx.z;
  const __bf16 *bAh, *bAl, *bBh, *bBl;
  long oC;
  if constexpr (NSYZ){
    if (z < 4){
      bAh = Ah + (long)z * CC; bAl = Al + (long)z * CC;
      bBh = tH + (long)z * CC; bBl = tL + (long)z * CC;
      oC = (long)z * CC;
    } else {
      const int zz = z - 4;
      bAh = tH + (long)zz * CC; bAl = tL + (long)zz * CC;
      bBh = Ah + (long)(4 + zz) * CC; bBl = Al + (long)(4 + zz) * CC;
      oC = (long)(4 + zz) * CC;
    }
  } else {
    bAh = Ah + (long)z * sAz; bAl = Al + (long)z * sAz;
    bBh = Bh + (long)z * sBz; bBl = Bl + (long)z * sBz;
    oC = (long)z * sCz;
  }
  const int i0 = blockIdx.x * 64;
  const int j0 = blockIdx.y * 64;
  const int tid = threadIdx.x;
  const int lane = tid & 63;
  const int w = tid >> 6;
  const int wr = (w >> 1) * 32, wc = (w & 1) * 32;
  const int lr = lane & 15;
  const int g = lane >> 4;

  const __bf16* pAh = bAh + (long)i0 * K;
  const __bf16* pAl = bAl + (long)i0 * K;
  const __bf16* pBh = bBh + (long)j0 * K;
  const __bf16* pBl = bBl + (long)j0 * K;

  f32x4 acc[2][2] = {};

  for (int kt = 0; kt < K; kt += 64){
#pragma unroll
    for (int p = 0; p < 2; ++p){
      const int t2 = p * 256 + tid;
      const int row = t2 >> 3;
      const int gs = (t2 & 7) ^ (row & 7);
      const long go = (long)row * K + kt + gs * 8;
      gld16(pAh + go, &sm[0][t2 * 8]);
      gld16(pAl + go, &sm[1][t2 * 8]);
      gld16(pBh + go, &sm[2][t2 * 8]);
      gld16(pBl + go, &sm[3][t2 * 8]);
    }
    __syncthreads();
#pragma unroll
    for (int ks = 0; ks < 2; ++ks){
      bf16x8 fa[2], fal[2], fb[2], fbl[2];
#pragma unroll
      for (int mi = 0; mi < 2; ++mi){
        const int row = wr + mi * 16 + lr;
        const int off = row * 64 + (((ks * 4 + g) ^ (row & 7)) * 8);
        fa[mi]  = *(const bf16x8*)(&sm[0][off]);
        fal[mi] = *(const bf16x8*)(&sm[1][off]);
      }
#pragma unroll
      for (int ni = 0; ni < 2; ++ni){
        const int row = wc + ni * 16 + lr;
        const int off = row * 64 + (((ks * 4 + g) ^ (row & 7)) * 8);
        fb[ni]  = *(const bf16x8*)(&sm[2][off]);
        fbl[ni] = *(const bf16x8*)(&sm[3][off]);
      }
#pragma unroll
      for (int mi = 0; mi < 2; ++mi)
#pragma unroll
        for (int ni = 0; ni < 2; ++ni){
          acc[mi][ni] = __builtin_amdgcn_mfma_f32_16x16x32_bf16(fa[mi],  fb[ni],  acc[mi][ni], 0, 0, 0);
          acc[mi][ni] = __builtin_amdgcn_mfma_f32_16x16x32_bf16(fa[mi],  fbl[ni], acc[mi][ni], 0, 0, 0);
          acc[mi][ni] = __builtin_amdgcn_mfma_f32_16x16x32_bf16(fal[mi], fb[ni],  acc[mi][ni], 0, 0, 0);
        }
    }
    __syncthreads();
  }

#pragma unroll
  for (int mi = 0; mi < 2; ++mi){
#pragma unroll
    for (int ni = 0; ni < 2; ++ni){
      const int col = j0 + wc + ni * 16 + lr;
#pragma unroll
      for (int j = 0; j < 4; ++j){
        const int row = i0 + wr + mi * 16 + g * 4 + j;
        float v = acc[mi][ni][j] * alpha;
        if (TMH) v = (((row == col) ? 3.f : 0.f) - v) * 0.5f;
        const long o = oC + (long)row * Nn + col;
        if (OUTMODE == 0){ Cf[o] = v; }
        else { __bf16 h = (__bf16)v; Coh[o] = h; Col[o] = (__bf16)(v - (float)h); }
      }
    }
  }
}

// ======================= fused corr+PV (bf16 E): res[n,c] = sum_m corr(E[n,m]) * h[c,m] =======================
// 64 n-rows x 128 c-cols, K-step 64, XOR-swizzled LDS, XCD-swizzled grid (64,4,2).
__global__ __launch_bounds__(256) void k_pv(
    const __bf16* __restrict__ E, const __bf16* __restrict__ Bh,
    const float* __restrict__ rm, const float* __restrict__ rsc,
    const float* __restrict__ mxv, const float* __restrict__ myv,
    __bf16* __restrict__ resH)
{
  __shared__ __align__(16) __bf16 sa[64 * 64];    // 8 KB
  __shared__ __align__(16) __bf16 sb[128 * 64];   // 16 KB
  const int z = blockIdx.z;
  int lin = blockIdx.y * 64 + blockIdx.x;         // 256 wgs -> cpx = 32
  lin = (lin & 7) * 32 + (lin >> 3);
  const int n0 = (lin & 63) * 64;
  const int c0 = (lin >> 6) * 128;
  const int tid = threadIdx.x;
  const int lane = tid & 63;
  const int w = tid >> 6;
  const int wr = (w >> 1) * 32, wc = (w & 1) * 64;
  const int lr = lane & 15, g = lane >> 4;

  const __bf16* pe = E + (long)z * NN + (long)n0 * N;
  const __bf16* pB = Bh + (long)z * CN + (long)c0 * N;

  const int ar = tid >> 2;          // row 0..63
  const int slot = tid & 3;         // covers granules slot*2, slot*2+1
  const float rmv = rm[(long)z * N + n0 + ar];
  const float rsv = rsc[(long)z * N + n0 + ar];
  const float tgt = mxv[n0 + ar];
  const __bf16* per = pe + (long)ar * N;

  f32x4 acc[2][4] = {};

  for (int kt = 0; kt < N; kt += 64){
    // E -> P (exp/mask/scale) -> sa, 16 elems per thread (granules gd = slot*2+d)
#pragma unroll
    for (int d = 0; d < 2; ++d){
      const int gd = slot * 2 + d;
      const bf16x8 ev = *(const bf16x8*)(per + kt + gd * 8);
      const float4 m0 = *(const float4*)(myv + kt + gd * 8);
      const float4 m1 = *(const float4*)(myv + kt + gd * 8 + 4);
      bf16x8 pk;
      pk[0] = (__bf16)((m0.x == tgt) ? __expf((float)ev[0] - rmv) * rsv : 0.f);
      pk[1] = (__bf16)((m0.y == tgt) ? __expf((float)ev[1] - rmv) * rsv : 0.f);
      pk[2] = (__bf16)((m0.z == tgt) ? __expf((float)ev[2] - rmv) * rsv : 0.f);
      pk[3] = (__bf16)((m0.w == tgt) ? __expf((float)ev[3] - rmv) * rsv : 0.f);
      pk[4] = (__bf16)((m1.x == tgt) ? __expf((float)ev[4] - rmv) * rsv : 0.f);
      pk[5] = (__bf16)((m1.y == tgt) ? __expf((float)ev[5] - rmv) * rsv : 0.f);
      pk[6] = (__bf16)((m1.z == tgt) ? __expf((float)ev[6] - rmv) * rsv : 0.f);
      pk[7] = (__bf16)((m1.w == tgt) ? __expf((float)ev[7] - rmv) * rsv : 0.f);
      *(bf16x8*)(&sa[ar * 64 + ((gd ^ (ar & 7)) * 8)]) = pk;
    }
    // stage B tile 128x64
#pragma unroll
    for (int p = 0; p < 4; ++p){
      const int t2 = p * 256 + tid;
      const int row = t2 >> 3;
      const int gs = (t2 & 7) ^ (row & 7);
      gld16(pB + (long)row * N + kt + gs * 8, &sb[t2 * 8]);
    }
    __syncthreads();
#pragma unroll
    for (int ks = 0; ks < 2; ++ks){
      bf16x8 fa[2], fb[4];
#pragma unroll
      for (int mi = 0; mi < 2; ++mi){
        const int row = wr + mi * 16 + lr;
        fa[mi] = *(const bf16x8*)(&sa[row * 64 + (((ks * 4 + g) ^ (row & 7)) * 8)]);
      }
#pragma unroll
      for (int ni = 0; ni < 4; ++ni){
        const int row = wc + ni * 16 + lr;
        fb[ni] = *(const bf16x8*)(&sb[row * 64 + (((ks * 4 + g) ^ (row & 7)) * 8)]);
      }
#pragma unroll
      for (int mi = 0; mi < 2; ++mi)
#pragma unroll
        for (int ni = 0; ni < 4; ++ni)
          acc[mi][ni] = __builtin_amdgcn_mfma_f32_16x16x32_bf16(fa[mi], fb[ni], acc[mi][ni], 0, 0, 0);
    }
    __syncthreads();
  }
#pragma unroll
  for (int mi = 0; mi < 2; ++mi)
#pragma unroll
    for (int ni = 0; ni < 4; ++ni){
      const int c = c0 + wc + ni * 16 + lr;
#pragma unroll
      for (int j = 0; j < 4; ++j){
        const int n = n0 + wr + mi * 16 + g * 4 + j;
        resH[(long)z * NC + (long)n * C + c] = (__bf16)acc[mi][ni][j];
      }
    }
}

// ======================= small helpers =======================
__global__ __launch_bounds__(256) void k_wtw(const float* __restrict__ A, const float* __restrict__ B,
                                             float* __restrict__ C2, float alpha){
  __shared__ float sa[16][32], sb[16][32];
  const int i0 = blockIdx.x * 32, j0 = blockIdx.y * 32;
  const int t = threadIdx.x;
  const int ti = t & 15, tj = t >> 4;
  const int li = t & 31, lc = t >> 5;
  float acc[2][2] = {};
  for (int cb = 0; cb < C; cb += 16){
    sa[lc][li]     = A[(long)(cb + lc) * C + i0 + li];
    sa[lc + 8][li] = A[(long)(cb + lc + 8) * C + i0 + li];
    sb[lc][li]     = B[(long)(cb + lc) * C + j0 + li];
    sb[lc + 8][li] = B[(long)(cb + lc + 8) * C + j0 + li];
    __syncthreads();
#pragma unroll
    for (int c = 0; c < 16; ++c){
      const float a0 = sa[c][ti * 2], a1 = sa[c][ti * 2 + 1];
      const float b0 = sb[c][tj * 2], b1 = sb[c][tj * 2 + 1];
      acc[0][0] = fmaf(a0, b0, acc[0][0]); acc[0][1] = fmaf(a0, b1, acc[0][1]);
      acc[1][0] = fmaf(a1, b0, acc[1][0]); acc[1][1] = fmaf(a1, b1, acc[1][1]);
    }
    __syncthreads();
  }
#pragma unroll
  for (int r = 0; r < 2; ++r)
#pragma unroll
    for (int s = 0; s < 2; ++s)
      C2[(long)(i0 + ti * 2 + r) * C + j0 + tj * 2 + s] = acc[r][s] * alpha;
}

__global__ __launch_bounds__(256) void k_wtv(const float* __restrict__ W, const float* __restrict__ b,
                                             float* __restrict__ u){
  __shared__ float sb2[C];
  const int t = threadIdx.x;
  sb2[t] = b[t]; sb2[t + 256] = b[t + 256];
  __syncthreads();
  const int e = blockIdx.x * 256 + t;
  float acc = 0.f;
  for (int c = 0; c < C; ++c) acc = fmaf(W[(long)c * C + e], sb2[c], acc);
  u[e] = acc;
}

__global__ void k_dot2(const float* __restrict__ a1, const float* __restrict__ b1,
                       const float* __restrict__ a2, const float* __restrict__ b2,
                       float* __restrict__ c0m2, float* __restrict__ c0s4){
  const int t = threadIdx.x;
  float s1 = 0.f, s2 = 0.f;
  for (int i = t; i < C; i += 256){ s1 += a1[i] * b1[i]; s2 += a2[i] * b2[i]; }
  __shared__ float sh1[4], sh2[4];
  s1 = wredSum(s1); s2 = wredSum(s2);
  if ((t & 63) == 0){ sh1[t >> 6] = s1; sh2[t >> 6] = s2; }
  __syncthreads();
  if (t == 0){
    float d1 = sh1[0] + sh1[1] + sh1[2] + sh1[3];
    float d2 = sh2[0] + sh2[1] + sh2[2] + sh2[3];
    c0m2[0] = d1; c0m2[1] = d1;
    c0s4[0] = d2; c0s4[1] = d2; c0s4[2] = d2; c0s4[3] = d2;
  }
}

__global__ __launch_bounds__(256) void k_pixvec(const __bf16* __restrict__ X, const float* __restrict__ u,
                                                float* __restrict__ out){
  const int z = blockIdx.y;
  const int wv = threadIdx.x >> 6, lane = threadIdx.x & 63;
  const int n = blockIdx.x * 4 + wv;
  float acc = 0.f;
  for (int d = lane; d < C; d += 64) acc += (float)X[(long)z * NC + (long)n * C + d] * u[d];
  acc = wredSum(acc);
  if (lane == 0) out[(long)z * N + n] = acc;
}

// ======================= prep / stats =======================
__global__ __launch_bounds__(256) void k_stats(const float* __restrict__ x, const float* __restrict__ y,
                                               float* __restrict__ meanv, float* __restrict__ invs){
  const int bid = blockIdx.x;
  const int t = bid >> 9, c = bid & 511;
  const float* src = (t < 2 ? x : y) + (long)(t & 1) * CN + (long)c * N;
  const int tid = threadIdx.x;
  float s1 = 0.f, s2 = 0.f;
  for (int i = tid; i < N; i += 256){ float v = src[i]; s1 += v; s2 += v * v; }
  __shared__ float sh1[4], sh2[4];
  s1 = wredSum(s1); s2 = wredSum(s2);
  if ((tid & 63) == 0){ sh1[tid >> 6] = s1; sh2[tid >> 6] = s2; }
  __syncthreads();
  if (tid == 0){
    float m = (sh1[0] + sh1[1] + sh1[2] + sh1[3]) * (1.f / (float)N);
    float ex2 = (sh2[0] + sh2[1] + sh2[2] + sh2[3]) * (1.f / (float)N);
    float var = ex2 - m * m;
    meanv[t * C + c] = m;
    invs[t * C + c] = rsqrtf((var > 0.f ? var : 0.f) + EPSC);
  }
}

__global__ __launch_bounds__(256) void k_prep(const float* __restrict__ src,
                                              const float* __restrict__ meanv, const float* __restrict__ invs, int toff,
                                              __bf16* __restrict__ adH,
                                              __bf16* __restrict__ fcH, __bf16* __restrict__ fcL,
                                              __bf16* __restrict__ ccH, __bf16* __restrict__ ccL,
                                              __bf16* __restrict__ rwH){
  __shared__ float tile[64][65];
  const int z = blockIdx.z;
  const int n0 = blockIdx.x * 64;
  const int c0 = blockIdx.y * 64;
  const int tid = threadIdx.x;
  const int tx = tid & 63, ty = tid >> 6;
  const int tgt = toff + z;
#pragma unroll
  for (int it = 0; it < 16; ++it){
    const int cc = it * 4 + ty;
    const float v = src[(long)z * CN + (long)(c0 + cc) * N + n0 + tx];
    tile[cc][tx] = v;
    const float cen = v - meanv[tgt * C + c0 + cc];
    splitw(cen, ccH, ccL, (long)tgt * CN + (long)(c0 + cc) * N + n0 + tx);
  }
  __syncthreads();
  const float m = meanv[tgt * C + c0 + tx];
  const float r = invs[tgt * C + c0 + tx];
#pragma unroll
  for (int it = 0; it < 16; ++it){
    const int p = it * 4 + ty;
    const float v = tile[tx][p];
    const float cen = v - m;
    const long o = (long)z * NC + (long)(n0 + p) * C + c0 + tx;
    adH[o] = (__bf16)(cen * r);
    splitw(cen, fcH, fcL, (long)tgt * NC + (long)(n0 + p) * C + c0 + tx);
    if (rwH) rwH[o] = (__bf16)v;
  }
}

__global__ __launch_bounds__(256) void k_wcvt(const float* __restrict__ s, __bf16* __restrict__ h,
                                              __bf16* __restrict__ l, int n){
  int i = blockIdx.x * 256 + threadIdx.x;
  if (i < n) splitw(s[i], h, l, i);
}
__global__ __launch_bounds__(256) void k_wcvt_h(const float* __restrict__ s, __bf16* __restrict__ h, int n){
  int i = blockIdx.x * 256 + threadIdx.x;
  if (i < n) h[i] = (__bf16)s[i];
}

// ======================= cov diag / power iteration / NS init =======================
__global__ void k_diag(float* __restrict__ cov){
  const int z = blockIdx.x, t = threadIdx.x;
  for (int i = t; i < C; i += 256) cov[(long)z * CC + (long)i * C + i] += 2.f * EPSC;
}

__global__ __launch_bounds__(256) void k_powit(const float* __restrict__ cov,
                                               float* __restrict__ invt, float* __restrict__ invsqt){
  __shared__ float v[C], red[4];
  const int z = blockIdx.x, t = threadIdx.x;
  const float* A = cov + (long)z * CC;
  const int j0 = t, j1 = t + 256;
  v[j0] = 1.f + 0.0003f * (float)j0;
  v[j1] = 1.f + 0.0003f * (float)j1;
  __syncthreads();
  float lam = 1.f;
  for (int it = 0; it < 8; ++it){
    float w0a = 0.f, w0b = 0.f, w1a = 0.f, w1b = 0.f;
#pragma unroll 4
    for (int c = 0; c < C; c += 2){
      const float vc0 = v[c], vc1 = v[c + 1];
      w0a = fmaf(A[(long)c * C + j0], vc0, w0a);
      w1a = fmaf(A[(long)c * C + j1], vc0, w1a);
      w0b = fmaf(A[(long)(c + 1) * C + j0], vc1, w0b);
      w1b = fmaf(A[(long)(c + 1) * C + j1], vc1, w1b);
    }
    const float w0 = w0a + w0b, w1 = w1a + w1b;
    float s = w0 * w0 + w1 * w1;
    s = wredSum(s);
    if ((t & 63) == 0) red[t >> 6] = s;
    __syncthreads();
    const float nrm = sqrtf(red[0] + red[1] + red[2] + red[3]);
    lam = nrm;
    const float inv = 1.f / nrm;
    v[j0] = w0 * inv;
    v[j1] = w1 * inv;
    __syncthreads();
  }
  if (t == 0){
    const float tt = 1.02f * lam;
    invt[z] = 1.f / tt;
    invsqt[z] = rsqrtf(tt);
  }
}

__global__ __launch_bounds__(256) void k_ns_init(const float* __restrict__ cov, const float* __restrict__ invt,
                                                 __bf16* __restrict__ h, __bf16* __restrict__ l,
                                                 __bf16* __restrict__ cph, __bf16* __restrict__ cpl){
  const int r = blockIdx.x, z = blockIdx.y;
  const long base = (long)z * CC + (long)r * C;
  const float it = invt[z];
  for (int i = threadIdx.x; i < C; i += 256){
    const float v = cov[base + i] * it;
    splitw(v, h, l, base + i);
    splitw(v, cph, cpl, base + i);
    h[4 * CC + base + i] = (__bf16)((i == r) ? 1.f : 0.f);
    l[4 * CC + base + i] = (__bf16)0.f;
  }
}

// ======================= fused online row-softmax + column accumulation (self path, fp32 E) ==============
__global__ __launch_bounds__(256) void k_rowcol(const float* __restrict__ E, float* __restrict__ partials){
  __shared__ float srm[16], srs[16];
  const int blk = blockIdx.x;
  const int r0 = blk * 16;
  const int tid = threadIdx.x;
  const int rr = tid >> 4;
  const int l16 = tid & 15;
  const float* pe = E + (long)(r0 + rr) * N;
  float m = -3.4e38f, s = 0.f;
  for (int i = l16 * 4; i < N; i += 64){
    const float4 v = *(const float4*)(pe + i);
    const float mv = fmaxf(fmaxf(v.x, v.y), fmaxf(v.z, v.w));
    if (mv > m){ s *= __expf(m - mv); m = mv; }
    s += __expf(v.x - m) + __expf(v.y - m) + __expf(v.z - m) + __expf(v.w - m);
  }
#pragma unroll
  for (int o = 8; o >= 1; o >>= 1){
    const float mo = __shfl_xor(m, o, 64);
    const float so = __shfl_xor(s, o, 64);
    const float nm = fmaxf(m, mo);
    s = s * __expf(m - nm) + so * __expf(mo - nm);
    m = nm;
  }
  if (l16 == 0){ srm[rr] = m; srs[rr] = 1.f / s; }
  __syncthreads();
  for (int j = tid * 4; j < N; j += 1024){
    float4 acc = {0.f, 0.f, 0.f, 0.f};
#pragma unroll
    for (int r = 0; r < 16; ++r){
      const float4 e4 = *(const float4*)(E + (long)(r0 + r) * N + j);
      const float rmv = srm[r], rsv = srs[r];
      acc.x += __expf(e4.x - rmv) * rsv;
      acc.y += __expf(e4.y - rmv) * rsv;
      acc.z += __expf(e4.z - rmv) * rsv;
      acc.w += __expf(e4.w - rmv) * rsv;
    }
    *(float4*)(partials + (long)blk * N + j) = acc;
  }
}

// two-stage deterministic column reduce (256 partials -> 16 -> att)
__global__ __launch_bounds__(256) void k_colreduce1(const float* __restrict__ partials, float* __restrict__ partials2){
  const int j = blockIdx.x * 256 + threadIdx.x;
  const int p0 = blockIdx.y * 16;
  float s = 0.f;
  for (int p = 0; p < 16; ++p) s += partials[(long)(p0 + p) * N + j];
  partials2[(long)blockIdx.y * N + j] = s;
}
__global__ __launch_bounds__(256) void k_colreduce2(const float* __restrict__ partials2, float* __restrict__ att){
  const int j = blockIdx.x * 256 + threadIdx.x;
  float s = 0.f;
  for (int p = 0; p < 16; ++p) s += partials2[(long)p * N + j];
  att[j] = s * (1.f / (float)N);
}

// ======================= main-path masked row stats (bf16 E), single-pass online =======================
__global__ __launch_bounds__(256) void k_rowstats1(
    const __bf16* __restrict__ E, const float* __restrict__ mx, const float* __restrict__ my,
    float* __restrict__ rowmax, float* __restrict__ rowscale)
{
  const int zz = blockIdx.y;
  const int r0 = blockIdx.x * 16;
  const int tid = threadIdx.x;
  const int rr = tid >> 4;
  const int l16 = tid & 15;
  const int row = r0 + rr;
  const __bf16* pe = E + (long)zz * NN + (long)row * N;
  const float target = mx[row];
  float m = -3.4e38f, s = 0.f, sm = 0.f;
  for (int i = l16 * 8; i < N; i += 128){
    const bf16x8 ev = *(const bf16x8*)(pe + i);
    const float4 w0 = *(const float4*)(my + i);
    const float4 w1 = *(const float4*)(my + i + 4);
    float e[8];
#pragma unroll
    for (int k = 0; k < 8; ++k) e[k] = (float)ev[k];
    float mv = fmaxf(fmaxf(fmaxf(e[0], e[1]), fmaxf(e[2], e[3])),
                     fmaxf(fmaxf(e[4], e[5]), fmaxf(e[6], e[7])));
    if (mv > m){ const float sc = __expf(m - mv); s *= sc; sm *= sc; m = mv; }
    float x0 = __expf(e[0] - m), x1 = __expf(e[1] - m), x2 = __expf(e[2] - m), x3 = __expf(e[3] - m);
    float x4 = __expf(e[4] - m), x5 = __expf(e[5] - m), x6 = __expf(e[6] - m), x7 = __expf(e[7] - m);
    s += ((x0 + x1) + (x2 + x3)) + ((x4 + x5) + (x6 + x7));
    if (w0.x == target) sm += x0;
    if (w0.y == target) sm += x1;
    if (w0.z == target) sm += x2;
    if (w0.w == target) sm += x3;
    if (w1.x == target) sm += x4;
    if (w1.y == target) sm += x5;
    if (w1.z == target) sm += x6;
    if (w1.w == target) sm += x7;
  }
#pragma unroll
  for (int o = 8; o >= 1; o >>= 1){
    const float mo = __shfl_xor(m, o, 64);
    const float so = __shfl_xor(s, o, 64);
    const float smo = __shfl_xor(sm, o, 64);
    const float nm = fmaxf(m, mo);
    const float sc0 = __expf(m - nm), sc1 = __expf(mo - nm);
    s = s * sc0 + so * sc1;
    sm = sm * sc0 + smo * sc1;
    m = nm;
  }
  if (l16 == 0){
    float l1 = sm / s;
    if (l1 < 1e-12f) l1 = 1e-12f;
    rowscale[(long)zz * N + row] = 1.f / (s * l1);
    rowmax[(long)zz * N + row] = m;
  }
}

// ======================= mask (radix select) =======================
__global__ __launch_bounds__(256) void k_radix(const float* __restrict__ a, float* __restrict__ thr){
  __shared__ unsigned int vals[N];
  __shared__ float shc[4];
  __shared__ unsigned int p_sh;
  __shared__ int k_sh;
  const float* pa = a + (long)blockIdx.x * N;
  const int tid = threadIdx.x;
  for (int i = tid; i < N; i += 256) vals[i] = __float_as_uint(pa[i]);
  if (tid == 0){ p_sh = 0u; k_sh = KSEL; }
  __syncthreads();
  for (int b = 31; b >= 0; --b){
    const unsigned int bit = 1u << b;
    const unsigned int above = (b == 31) ? 0u : ~((bit << 1) - 1u);
    const unsigned int p = p_sh;
    int cnt = 0;
    for (int i = tid; i < N; i += 256){
      unsigned int v = vals[i];
      if ((v & above) == p && (v & bit)) cnt++;
    }
    float cf = wredSum((float)cnt);
    if ((tid & 63) == 0) shc[tid >> 6] = cf;
    __syncthreads();
    if (tid == 0){
      int c1 = (int)(shc[0] + shc[1] + shc[2] + shc[3] + 0.5f);
      if (k_sh <= c1) p_sh = p | bit;
      else k_sh -= c1;
    }
    __syncthreads();
  }
  if (tid == 0) thr[blockIdx.x] = __uint_as_float(p_sh);
}

__global__ __launch_bounds__(256) void k_mask(const float* __restrict__ ax, const float* __restrict__ ay,
                                              const float* __restrict__ thr, float* __restrict__ mx,
                                              float* __restrict__ my){
  int j = blockIdx.x * 256 + threadIdx.x;
  mx[j] = (ax[j] >= thr[0] && ax[N + j] >= thr[1]) ? 1.f : 0.f;
  my[j] = (ay[j] >= thr[2] && ay[N + j] >= thr[3]) ? 1.f : 0.f;
}

// ======================= host =======================
extern "C" void kernel_launch(void* const* d_in, const int* in_sizes, int n_in,
                              void* d_out, int out_size, void* d_ws, size_t ws_size,
                              hipStream_t stream)
{
  const float* x     = (const float*)d_in[0];
  const float* y     = (const float*)d_in[1];
  const float* f_w   = (const float*)d_in[2];
  const float* f_b   = (const float*)d_in[3];
  const float* g_w   = (const float*)d_in[4];
  const float* g_b   = (const float*)d_in[5];
  const float* saf_w = (const float*)d_in[6];
  const float* saf_b = (const float*)d_in[7];
  const float* sag_w = (const float*)d_in[8];
  const float* sag_b = (const float*)d_in[9];
  const float* h_w   = (const float*)d_in[10];
  const float* h_b   = (const float*)d_in[11];
  const float* ow    = (const float*)d_in[12];
  const float* ob    = (const float*)d_in[13];

  const size_t MBy = 1ull << 20;
  char* base = (char*)d_ws;
  if (ws_size < 206 * MBy) return;
  auto F  = [&](size_t off){ return (float*)(base + off); };
  auto Bp = [&](size_t off){ return (__bf16*)(base + off); };

  // ---- E region: self E0 fp32 [N][N] at [0,64); main Ebf bf16 [2][N][N] at [0,64)
  float *E0 = F(0);
  __bf16 *Ebf = Bp(0);
  __bf16 *ccH = Bp(0), *ccL = Bp(16*MBy);            // [4][C][N] pairs, dies @cov
  float  *covb = F(32*MBy);                          // [4][C][C]
  __bf16 *zpolH = Bp(36*MBy), *zpolL = Bp(38*MBy);   // [4][C][C] pairs
  __bf16 *covPH = Bp(40*MBy), *covPL = Bp(42*MBy);
  float  *KsTf = F(44*MBy), *K2tf = F(45*MBy);
  __bf16 *KsTH = Bp(46*MBy), *KsTL = Bp(46*MBy + 512*1024);
  __bf16 *K2tH = Bp(47*MBy), *hwH = Bp(47*MBy + 512*1024);
  __bf16 *tpH = Bp(48*MBy), *tpL = Bp(50*MBy);       // NS T scratch
  __bf16 *xaH = Bp(64*MBy);                          // dies @zca write
  __bf16 *xzH = Bp(64*MBy), *xzL = Bp(80*MBy);       // [4][N][C] pairs
  __bf16 *ypmH = Bp(96*MBy);                         // dies @hconv
  __bf16 *AsH = Bp(96*MBy), *AsL = Bp(112*MBy);      // [4][N][C] pairs
  // [128,160): fc pairs (die @zca apply) -> resH afterwards (outside all E)
  __bf16 *fcH = Bp(128*MBy), *fcL = Bp(144*MBy);
  __bf16 *resH = Bp(128*MBy);                        // [2][N][C]
  // [160,176): NS ping-pong [Y(0-3)|Z(4-7)] pairs
  __bf16 *nsAh = Bp(160*MBy), *nsAl = Bp(164*MBy);
  __bf16 *nsBh = Bp(168*MBy), *nsBl = Bp(172*MBy);
  // [176,205): persistent
  __bf16 *A2H = Bp(176*MBy);
  __bf16 *yaH = Bp(184*MBy);
  __bf16 *hH  = Bp(192*MBy);
  __bf16 *owH = Bp(200*MBy);                         // [200, 200.5)
  size_t so = 200 * MBy + 512 * 1024;                // smalls [200.5, 201)
  auto SF = [&](size_t bytes){ float* p = F(so); so += bytes; return p; };
  float *meanv = SF(8*1024), *invs = SF(8*1024);
  float *rm = SF(32*1024), *rsc = SF(32*1024);
  float *mxv = SF(16*1024), *myv = SF(16*1024);
  float *rvec2 = SF(32*1024), *cvec2 = SF(32*1024);
  float *rvS = SF(64*1024), *cvS = SF(64*1024);
  float *u1m = SF(2*1024), *u2m = SF(2*1024), *u1s = SF(2*1024), *u2s = SF(2*1024);
  float *c0m2 = SF(64), *c0s4 = SF(64), *thr = SF(64);
  float *invt = SF(64), *invsqt = SF(64);
  float *partials = F(201*MBy);                      // [256][N] f32 = 4MB, [201,205)
  float *partials2 = F(205*MBy);                     // [16][N] f32 = 256KB

  float* outm = (float*)d_out;               // [2][C][N]
  float* attx = outm + B2 * CN;              // [2][N]
  float* atty = attx + (long)B2 * N;

  // 1) stats + prep
  k_stats<<<dim3(4 * C), dim3(256), 0, stream>>>(x, y, meanv, invs);
  k_prep<<<dim3(64, 8, 2), dim3(256), 0, stream>>>(x, meanv, invs, 0, xaH, fcH, fcL, ccH, ccL, nullptr);
  k_prep<<<dim3(64, 8, 2), dim3(256), 0, stream>>>(y, meanv, invs, 2, yaH, fcH, fcL, ccH, ccL, ypmH);

  // 2) weight products & conversions
  k_wtw<<<dim3(16, 16), dim3(256), 0, stream>>>(sag_w, saf_w, KsTf, 1.f);
  k_wtw<<<dim3(16, 16), dim3(256), 0, stream>>>(g_w, f_w, K2tf, 1.f);
  {
    const int nb = (int)(CC / 256);
    k_wcvt<<<nb, 256, 0, stream>>>(KsTf, KsTH, KsTL, (int)CC);
    k_wcvt_h<<<nb, 256, 0, stream>>>(K2tf, K2tH, (int)CC);
    k_wcvt_h<<<nb, 256, 0, stream>>>(h_w, hwH, (int)CC);
    k_wcvt_h<<<nb, 256, 0, stream>>>(ow, owH, (int)CC);
  }
  k_wtv<<<dim3(2), dim3(256), 0, stream>>>(g_w, f_b, u1m);
  k_wtv<<<dim3(2), dim3(256), 0, stream>>>(f_w, g_b, u2m);
  k_wtv<<<dim3(2), dim3(256), 0, stream>>>(sag_w, saf_b, u1s);
  k_wtv<<<dim3(2), dim3(256), 0, stream>>>(saf_w, sag_b, u2s);
  k_dot2<<<dim3(1), dim3(256), 0, stream>>>(f_b, g_b, saf_b, sag_b, c0m2, c0s4);
  k_pixvec<<<dim3(N / 4, 2), dim3(256), 0, stream>>>(xaH, u2m, rvec2);
  k_pixvec<<<dim3(N / 4, 2), dim3(256), 0, stream>>>(yaH, u1m, cvec2);

  // 3) cov + 2eps*I + power-iteration lambda_max
  k_mm64<0,0,0><<<dim3(8, 8, 4), dim3(256), 0, stream>>>(
      ccH, ccL, ccH, ccL, nullptr, nullptr, covb, nullptr, nullptr, C, N, CN, CN, CC, 1.f / (float)(N - 1));
  k_diag<<<dim3(4), dim3(256), 0, stream>>>(covb);
  k_powit<<<dim3(4), dim3(256), 0, stream>>>(covb, invt, invsqt);

  // 4) A2 = xa . K2^T, h conv
  k_mm<1,0,2><<<dim3(32, 4, 2), dim3(256), 0, stream>>>(xaH, nullptr, K2tH, nullptr, nullptr, A2H, nullptr,
      C, C, NC, 0, NC, 1.f, nullptr, nullptr, 0, nullptr, 0, nullptr, nullptr, 0);
  k_mm<1,0,2><<<dim3(4, 32, 2), dim3(256), 0, stream>>>(hwH, nullptr, ypmH, nullptr, nullptr, hH, nullptr,
      N, C, 0, NC, CN, 1.f, nullptr, h_b, 0, nullptr, 0, nullptr, nullptr, 0);

  // 5) Newton-Schulz (5 iters) + split-bf16 polish
  k_ns_init<<<dim3(C, 4), dim3(256), 0, stream>>>(covb, invt, nsAh, nsAl, covPH, covPL);
  __bf16 *cah = nsAh, *cal = nsAl, *cbh = nsBh, *cbl = nsBl;
  for (int it = 0; it < NS_ITERS; ++it){
    k_mm64<1,1,0><<<dim3(8, 8, 4), dim3(256), 0, stream>>>(
        cah + 4*CC, cal + 4*CC, cah, cal, nullptr, nullptr, nullptr, tpH, tpL, C, C, CC, CC, CC, 1.f);
    k_mm64<0,1,1><<<dim3(8, 8, 8), dim3(256), 0, stream>>>(
        cah, cal, nullptr, nullptr, tpH, tpL, nullptr, cbh, cbl, C, C, CC, CC, CC, 1.f);
    __bf16* t;
    t = cah; cah = cbh; cbh = t;
    t = cal; cal = cbl; cbl = t;
  }
  k_mm64<0,1,0><<<dim3(8, 8, 4), dim3(256), 0, stream>>>(
      cah + 4*CC, cal + 4*CC, cah + 4*CC, cal + 4*CC, nullptr, nullptr, nullptr, tpH, tpL, C, C, CC, CC, CC, 1.f);
  k_mm64<1,1,0><<<dim3(8, 8, 4), dim3(256), 0, stream>>>(
      covPH, covPL, tpH, tpL, nullptr, nullptr, nullptr, cbh, cbl, C, C, CC, CC, CC, 1.f);
  k_mm64<0,1,0><<<dim3(8, 8, 4), dim3(256), 0, stream>>>(
      cah + 4*CC, cal + 4*CC, cbh, cbl, nullptr, nullptr, nullptr, zpolH, zpolL, C, C, CC, CC, CC, 1.f);

  // 6) zca apply: xz = invsqt * fc . Z
  k_mm<3,0,1><<<dim3(32, 4, 4), dim3(256), 0, stream>>>(fcH, fcL, zpolH, zpolL, nullptr, xzH, xzL,
      C, C, NC, CC, NC, 1.f, invsqt, nullptr, 0, nullptr, 0, nullptr, nullptr, 0);

  // 6.5) self bias vecs + As = xz . Ks^T
  k_pixvec<<<dim3(N / 4, 4), dim3(256), 0, stream>>>(xzH, u2s, rvS);
  k_pixvec<<<dim3(N / 4, 4), dim3(256), 0, stream>>>(xzH, u1s, cvS);
  k_mm<3,0,1><<<dim3(32, 4, 4), dim3(256), 0, stream>>>(xzH, xzL, KsTH, KsTL, nullptr, AsH, AsL,
      C, C, NC, 0, NC, 1.f, nullptr, nullptr, 0, nullptr, 0, nullptr, nullptr, 0);

  // 7) self-attention energies -> atten (fp32 E, rank-sensitive path)
  for (int z = 0; z < 4; ++z){
    k_mm<3,0,0><<<dim3(32, 32, 1), dim3(256), 0, stream>>>(AsH + (long)z*NC, AsL + (long)z*NC,
        xzH + (long)z*NC, xzL + (long)z*NC, E0, nullptr, nullptr,
        N, C, 0, 0, 0, 1.f, nullptr, rvS + (long)z*N, 0, cvS + (long)z*N, 0, c0s4, nullptr, 0);
    k_rowcol<<<dim3(N / 16), dim3(256), 0, stream>>>(E0, partials);
    k_colreduce1<<<dim3(16, 16), dim3(256), 0, stream>>>(partials, partials2);
    k_colreduce2<<<dim3(16), dim3(256), 0, stream>>>(partials2, (z < 2 ? attx : atty) + (long)(z & 1) * N);
  }

  // 8) masks
  k_radix<<<dim3(2), dim3(256), 0, stream>>>(attx, thr);
  k_radix<<<dim3(2), dim3(256), 0, stream>>>(atty, thr + 2);
  k_mask<<<dim3(16), dim3(256), 0, stream>>>(attx, atty, thr, mxv, myv);

  // 9) main path: energy -> bf16 E; online masked rowstats; fused corr+PV; out conv
  k_mm<1,0,2><<<dim3(32, 32, 2), dim3(256), 0, stream>>>(A2H, nullptr, yaH, nullptr, nullptr, Ebf, nullptr,
      N, C, NC, NC, NN, 1.f, nullptr, rvec2, N, cvec2, N, c0m2, nullptr, 0);
  k_rowstats1<<<dim3(N / 16, 2), dim3(256), 0, stream>>>(Ebf, mxv, myv, rm, rsc);
  k_pv<<<dim3(64, 4, 2), dim3(256), 0, stream>>>(Ebf, hH, rm, rsc, mxv, myv, resH);
  k_mm<1,0,0><<<dim3(4, 32, 2), dim3(256), 0, stream>>>(owH, nullptr, resH, nullptr, outm, nullptr, nullptr,
      N, C, 0, NC, CN, 1.f, nullptr, ob, 0, nullptr, 0, nullptr, x, CN);
}

// Round 9
// 1271.920 us; speedup vs baseline: 1.1261x; 1.0757x over previous
//
#include <hip/hip_runtime.h>
#include <cstdint>

static constexpr int B2 = 2;
static constexpr int C = 512;
static constexpr int N = 4096;
static constexpr long CN = (long)C * N;
static constexpr long NC = (long)N * C;
static constexpr long CC = (long)C * C;
static constexpr long NN = (long)N * N;
static constexpr float EPSC = 1e-5f;
static constexpr int KSEL = 308;       // N - int(N*0.925)
static constexpr int NS_ITERS = 4;

typedef __attribute__((ext_vector_type(8))) __bf16 bf16x8;
typedef __attribute__((ext_vector_type(4))) float f32x4;

__device__ __forceinline__ float wredSum(float v){
#pragma unroll
  for (int o = 32; o >= 1; o >>= 1) v += __shfl_xor(v, o, 64);
  return v;
}

__device__ __forceinline__ void gld16(const __bf16* g, __bf16* l){
  __builtin_amdgcn_global_load_lds(
      (const __attribute__((address_space(1))) void*)g,
      (__attribute__((address_space(3))) void*)l, 16, 0, 0);
}

__device__ __forceinline__ void splitw(float v, __bf16* ph, __bf16* pl, long o){
  __bf16 h = (__bf16)v;
  ph[o] = h;
  pl[o] = (__bf16)(v - (float)h);
}

// ======================= split/plain bf16 MFMA GEMM, 128x128 tile, BK=32 =======================
// XCD-aware block swizzle. ROWP=1: epilogue also emits per-(block,row) softmax partials (m,s).
template<int PASSES, int TMH, int OUTMODE, int ROWP>
__global__ __launch_bounds__(256) void k_mm(
    const __bf16* __restrict__ Ah, const __bf16* __restrict__ Al,
    const __bf16* __restrict__ Bh, const __bf16* __restrict__ Bl,
    float* __restrict__ Cf, __bf16* __restrict__ Coh, __bf16* __restrict__ Col,
    int Nn, int K, long sAz, long sBz, long sCz,
    float alpha, const float* __restrict__ alpha_ptr,
    const float* __restrict__ brow, long sBr,
    const float* __restrict__ bcol, long sBc,
    const float* __restrict__ c0p,
    const float* __restrict__ addsrc, long sAddz,
    float* __restrict__ Pm, float* __restrict__ Ps)
{
  constexpr int NB = (PASSES == 3) ? 4 : 2;
  constexpr int SB = (PASSES == 3) ? 2 : 1;
  __shared__ __align__(16) __bf16 sm[NB][128 * 32];
  __shared__ float pmx[2][128], psx[2][128];
  const int z = blockIdx.z;
  const int nwx = gridDim.x;
  int lin = blockIdx.y * nwx + blockIdx.x;
  const int nwg = nwx * gridDim.y;
  if ((nwg & 7) == 0){
    const int cpx = nwg >> 3;
    lin = (lin & 7) * cpx + (lin >> 3);
  }
  const int i0 = (lin % nwx) * 128;
  const int j0 = (lin / nwx) * 128;
  const int tid = threadIdx.x;
  const int lane = tid & 63;
  const int w = tid >> 6;
  const int wr = (w >> 1) * 64, wc = (w & 1) * 64;
  const int lr = lane & 15;
  const int g = lane >> 4;

  const __bf16* pAh = Ah + (long)z * sAz + (long)i0 * K;
  const __bf16* pBh = Bh + (long)z * sBz + (long)j0 * K;
  const __bf16* pAl = (PASSES == 3) ? (Al + (long)z * sAz + (long)i0 * K) : nullptr;
  const __bf16* pBl = (PASSES == 3) ? (Bl + (long)z * sBz + (long)j0 * K) : nullptr;

  f32x4 acc[4][4] = {};

  for (int kt = 0; kt < K; kt += 32){
#pragma unroll
    for (int p = 0; p < 2; ++p){
      const int t2 = p * 256 + tid;
      const int row = t2 >> 2;
      const int gs = (t2 & 3) ^ ((row >> 1) & 3);
      const long go = (long)row * K + kt + gs * 8;
      gld16(pAh + go, &sm[0][t2 * 8]);
      gld16(pBh + go, &sm[SB][t2 * 8]);
      if constexpr (PASSES == 3){
        gld16(pAl + go, &sm[1][t2 * 8]);
        gld16(pBl + go, &sm[3][t2 * 8]);
      }
    }
    __syncthreads();
    bf16x8 fa[4], fal[4], fb[4], fbl[4];
#pragma unroll
    for (int mi = 0; mi < 4; ++mi){
      const int row = wr + mi * 16 + lr;
      const int off = row * 32 + ((g ^ ((row >> 1) & 3)) * 8);
      fa[mi] = *(const bf16x8*)(&sm[0][off]);
      if constexpr (PASSES == 3) fal[mi] = *(const bf16x8*)(&sm[1][off]);
    }
#pragma unroll
    for (int ni = 0; ni < 4; ++ni){
      const int row = wc + ni * 16 + lr;
      const int off = row * 32 + ((g ^ ((row >> 1) & 3)) * 8);
      fb[ni] = *(const bf16x8*)(&sm[SB][off]);
      if constexpr (PASSES == 3) fbl[ni] = *(const bf16x8*)(&sm[3][off]);
    }
#pragma unroll
    for (int mi = 0; mi < 4; ++mi)
#pragma unroll
      for (int ni = 0; ni < 4; ++ni){
        acc[mi][ni] = __builtin_amdgcn_mfma_f32_16x16x32_bf16(fa[mi], fb[ni], acc[mi][ni], 0, 0, 0);
        if constexpr (PASSES == 3){
          acc[mi][ni] = __builtin_amdgcn_mfma_f32_16x16x32_bf16(fa[mi],  fbl[ni], acc[mi][ni], 0, 0, 0);
          acc[mi][ni] = __builtin_amdgcn_mfma_f32_16x16x32_bf16(fal[mi], fb[ni],  acc[mi][ni], 0, 0, 0);
        }
      }
    __syncthreads();
  }

  float al2 = alpha;
  if (alpha_ptr) al2 *= alpha_ptr[z];
  const float c0v = c0p ? c0p[z] : 0.f;
#pragma unroll
  for (int mi = 0; mi < 4; ++mi){
    float mrow[4] = {-3.4e38f, -3.4e38f, -3.4e38f, -3.4e38f};
    float srow[4] = {0.f, 0.f, 0.f, 0.f};
#pragma unroll
    for (int ni = 0; ni < 4; ++ni){
      const int col = j0 + wc + ni * 16 + lr;
      const float bc = (bcol ? bcol[z * sBc + col] : 0.f) + c0v;
#pragma unroll
      for (int j = 0; j < 4; ++j){
        const int row = i0 + wr + mi * 16 + g * 4 + j;
        float v = acc[mi][ni][j] * al2;
        if (TMH) v = (((row == col) ? 3.f : 0.f) - v) * 0.5f;
        if (brow) v += brow[z * sBr + row];
        v += bc;
        if (addsrc) v += addsrc[(long)z * sAddz + (long)row * Nn + col];
        const long o = (long)z * sCz + (long)row * Nn + col;
        if (OUTMODE == 0){ Cf[o] = v; }
        else if (OUTMODE == 1){ __bf16 h = (__bf16)v; Coh[o] = h; Col[o] = (__bf16)(v - (float)h); }
        else { Coh[o] = (__bf16)v; }
        if constexpr (ROWP){
          if (v > mrow[j]){ srow[j] *= __expf(mrow[j] - v); mrow[j] = v; }
          srow[j] += __expf(v - mrow[j]);
        }
      }
    }
    if constexpr (ROWP){
#pragma unroll
      for (int j = 0; j < 4; ++j){
        float m = mrow[j], s = srow[j];
#pragma unroll
        for (int o = 1; o <= 8; o <<= 1){
          const float mo = __shfl_xor(m, o, 64);
          const float so = __shfl_xor(s, o, 64);
          const float nm = fmaxf(m, mo);
          s = s * __expf(m - nm) + so * __expf(mo - nm);
          m = nm;
        }
        if (lr == 0){
          const int rl = wr + mi * 16 + g * 4 + j;
          pmx[w & 1][rl] = m;
          psx[w & 1][rl] = s;
        }
      }
    }
  }
  if constexpr (ROWP){
    __syncthreads();
    if (tid < 128){
      const float m0 = pmx[0][tid], s0 = psx[0][tid];
      const float m1 = pmx[1][tid], s1 = psx[1][tid];
      const float nm = fmaxf(m0, m1);
      const float s = s0 * __expf(m0 - nm) + s1 * __expf(m1 - nm);
      Pm[(long)(j0 >> 7) * N + i0 + tid] = nm;
      Ps[(long)(j0 >> 7) * N + i0 + tid] = s;
    }
  }
}

// ======================= split-bf16 MFMA GEMM, 64x64 tile, BK=64 (always 3-pass) =======================
template<int TMH, int OUTMODE, int NSYZ>
__global__ __launch_bounds__(256) void k_mm64(
    const __bf16* __restrict__ Ah, const __bf16* __restrict__ Al,
    const __bf16* __restrict__ Bh, const __bf16* __restrict__ Bl,
    const __bf16* __restrict__ tH, const __bf16* __restrict__ tL,
    float* __restrict__ Cf, __bf16* __restrict__ Coh, __bf16* __restrict__ Col,
    int Nn, int K, long sAz, long sBz, long sCz, float alpha)
{
  __shared__ __align__(16) __bf16 sm[4][64 * 64];
  const int z = blockIdx.z;
  const __bf16 *bAh, *bAl, *bBh, *bBl;
  long oC;
  if constexpr (NSYZ){
    if (z < 4){
      bAh = Ah + (long)z * CC; bAl = Al + (long)z * CC;
      bBh = tH + (long)z * CC; bBl = tL + (long)z * CC;
      oC = (long)z * CC;
    } else {
      const int zz = z - 4;
      bAh = tH + (long)zz * CC; bAl = tL + (long)zz * CC;
      bBh = Ah + (long)(4 + zz) * CC; bBl = Al + (long)(4 + zz) * CC;
      oC = (long)(4 + zz) * CC;
    }
  } else {
    bAh = Ah + (long)z * sAz; bAl = Al + (long)z * sAz;
    bBh = Bh + (long)z * sBz; bBl = Bl + (long)z * sBz;
    oC = (long)z * sCz;
  }
  const int i0 = blockIdx.x * 64;
  const int j0 = blockIdx.y * 64;
  const int tid = threadIdx.x;
  const int lane = tid & 63;
  const int w = tid >> 6;
  const int wr = (w >> 1) * 32, wc = (w & 1) * 32;
  const int lr = lane & 15;
  const int g = lane >> 4;

  const __bf16* pAh = bAh + (long)i0 * K;
  const __bf16* pAl = bAl + (long)i0 * K;
  const __bf16* pBh = bBh + (long)j0 * K;
  const __bf16* pBl = bBl + (long)j0 * K;

  f32x4 acc[2][2] = {};

  for (int kt = 0; kt < K; kt += 64){
#pragma unroll
    for (int p = 0; p < 2; ++p){
      const int t2 = p * 256 + tid;
      const int row = t2 >> 3;
      const int gs = (t2 & 7) ^ (row & 7);
      const long go = (long)row * K + kt + gs * 8;
      gld16(pAh + go, &sm[0][t2 * 8]);
      gld16(pAl + go, &sm[1][t2 * 8]);
      gld16(pBh + go, &sm[2][t2 * 8]);
      gld16(pBl + go, &sm[3][t2 * 8]);
    }
    __syncthreads();
#pragma unroll
    for (int ks = 0; ks < 2; ++ks){
      bf16x8 fa[2], fal[2], fb[2], fbl[2];
#pragma unroll
      for (int mi = 0; mi < 2; ++mi){
        const int row = wr + mi * 16 + lr;
        const int off = row * 64 + (((ks * 4 + g) ^ (row & 7)) * 8);
        fa[mi]  = *(const bf16x8*)(&sm[0][off]);
        fal[mi] = *(const bf16x8*)(&sm[1][off]);
      }
#pragma unroll
      for (int ni = 0; ni < 2; ++ni){
        const int row = wc + ni * 16 + lr;
        const int off = row * 64 + (((ks * 4 + g) ^ (row & 7)) * 8);
        fb[ni]  = *(const bf16x8*)(&sm[2][off]);
        fbl[ni] = *(const bf16x8*)(&sm[3][off]);
      }
#pragma unroll
      for (int mi = 0; mi < 2; ++mi)
#pragma unroll
        for (int ni = 0; ni < 2; ++ni){
          acc[mi][ni] = __builtin_amdgcn_mfma_f32_16x16x32_bf16(fa[mi],  fb[ni],  acc[mi][ni], 0, 0, 0);
          acc[mi][ni] = __builtin_amdgcn_mfma_f32_16x16x32_bf16(fa[mi],  fbl[ni], acc[mi][ni], 0, 0, 0);
          acc[mi][ni] = __builtin_amdgcn_mfma_f32_16x16x32_bf16(fal[mi], fb[ni],  acc[mi][ni], 0, 0, 0);
        }
    }
    __syncthreads();
  }

#pragma unroll
  for (int mi = 0; mi < 2; ++mi){
#pragma unroll
    for (int ni = 0; ni < 2; ++ni){
      const int col = j0 + wc + ni * 16 + lr;
#pragma unroll
      for (int j = 0; j < 4; ++j){
        const int row = i0 + wr + mi * 16 + g * 4 + j;
        float v = acc[mi][ni][j] * alpha;
        if (TMH) v = (((row == col) ? 3.f : 0.f) - v) * 0.5f;
        const long o = oC + (long)row * Nn + col;
        if (OUTMODE == 0){ Cf[o] = v; }
        else { __bf16 h = (__bf16)v; Coh[o] = h; Col[o] = (__bf16)(v - (float)h); }
      }
    }
  }
}

// ======================= fused corr+PV (bf16 E) =======================
__global__ __launch_bounds__(256) void k_pv(
    const __bf16* __restrict__ E, const __bf16* __restrict__ Bh,
    const float* __restrict__ rm, const float* __restrict__ rsc,
    const float* __restrict__ mxv, const float* __restrict__ myv,
    __bf16* __restrict__ resH)
{
  __shared__ __align__(16) __bf16 sa[64 * 64];
  __shared__ __align__(16) __bf16 sb[128 * 64];
  const int z = blockIdx.z;
  int lin = blockIdx.y * 64 + blockIdx.x;
  lin = (lin & 7) * 32 + (lin >> 3);
  const int n0 = (lin & 63) * 64;
  const int c0 = (lin >> 6) * 128;
  const int tid = threadIdx.x;
  const int lane = tid & 63;
  const int w = tid >> 6;
  const int wr = (w >> 1) * 32, wc = (w & 1) * 64;
  const int lr = lane & 15, g = lane >> 4;

  const __bf16* pe = E + (long)z * NN + (long)n0 * N;
  const __bf16* pB = Bh + (long)z * CN + (long)c0 * N;

  const int ar = tid >> 2;
  const int slot = tid & 3;
  const float rmv = rm[(long)z * N + n0 + ar];
  const float rsv = rsc[(long)z * N + n0 + ar];
  const float tgt = mxv[n0 + ar];
  const __bf16* per = pe + (long)ar * N;

  f32x4 acc[2][4] = {};

  for (int kt = 0; kt < N; kt += 64){
#pragma unroll
    for (int d = 0; d < 2; ++d){
      const int gd = slot * 2 + d;
      const bf16x8 ev = *(const bf16x8*)(per + kt + gd * 8);
      const float4 m0 = *(const float4*)(myv + kt + gd * 8);
      const float4 m1 = *(const float4*)(myv + kt + gd * 8 + 4);
      bf16x8 pk;
      pk[0] = (__bf16)((m0.x == tgt) ? __expf((float)ev[0] - rmv) * rsv : 0.f);
      pk[1] = (__bf16)((m0.y == tgt) ? __expf((float)ev[1] - rmv) * rsv : 0.f);
      pk[2] = (__bf16)((m0.z == tgt) ? __expf((float)ev[2] - rmv) * rsv : 0.f);
      pk[3] = (__bf16)((m0.w == tgt) ? __expf((float)ev[3] - rmv) * rsv : 0.f);
      pk[4] = (__bf16)((m1.x == tgt) ? __expf((float)ev[4] - rmv) * rsv : 0.f);
      pk[5] = (__bf16)((m1.y == tgt) ? __expf((float)ev[5] - rmv) * rsv : 0.f);
      pk[6] = (__bf16)((m1.z == tgt) ? __expf((float)ev[6] - rmv) * rsv : 0.f);
      pk[7] = (__bf16)((m1.w == tgt) ? __expf((float)ev[7] - rmv) * rsv : 0.f);
      *(bf16x8*)(&sa[ar * 64 + ((gd ^ (ar & 7)) * 8)]) = pk;
    }
#pragma unroll
    for (int p = 0; p < 4; ++p){
      const int t2 = p * 256 + tid;
      const int row = t2 >> 3;
      const int gs = (t2 & 7) ^ (row & 7);
      gld16(pB + (long)row * N + kt + gs * 8, &sb[t2 * 8]);
    }
    __syncthreads();
#pragma unroll
    for (int ks = 0; ks < 2; ++ks){
      bf16x8 fa[2], fb[4];
#pragma unroll
      for (int mi = 0; mi < 2; ++mi){
        const int row = wr + mi * 16 + lr;
        fa[mi] = *(const bf16x8*)(&sa[row * 64 + (((ks * 4 + g) ^ (row & 7)) * 8)]);
      }
#pragma unroll
      for (int ni = 0; ni < 4; ++ni){
        const int row = wc + ni * 16 + lr;
        fb[ni] = *(const bf16x8*)(&sb[row * 64 + (((ks * 4 + g) ^ (row & 7)) * 8)]);
      }
#pragma unroll
      for (int mi = 0; mi < 2; ++mi)
#pragma unroll
        for (int ni = 0; ni < 4; ++ni)
          acc[mi][ni] = __builtin_amdgcn_mfma_f32_16x16x32_bf16(fa[mi], fb[ni], acc[mi][ni], 0, 0, 0);
    }
    __syncthreads();
  }
#pragma unroll
  for (int mi = 0; mi < 2; ++mi)
#pragma unroll
    for (int ni = 0; ni < 4; ++ni){
      const int c = c0 + wc + ni * 16 + lr;
#pragma unroll
      for (int j = 0; j < 4; ++j){
        const int n = n0 + wr + mi * 16 + g * 4 + j;
        resH[(long)z * NC + (long)n * C + c] = (__bf16)acc[mi][ni][j];
      }
    }
}

// ======================= small helpers =======================
__global__ __launch_bounds__(256) void k_wtw(const float* __restrict__ A, const float* __restrict__ B,
                                             float* __restrict__ C2, float alpha){
  __shared__ float sa[16][32], sb[16][32];
  const int i0 = blockIdx.x * 32, j0 = blockIdx.y * 32;
  const int t = threadIdx.x;
  const int ti = t & 15, tj = t >> 4;
  const int li = t & 31, lc = t >> 5;
  float acc[2][2] = {};
  for (int cb = 0; cb < C; cb += 16){
    sa[lc][li]     = A[(long)(cb + lc) * C + i0 + li];
    sa[lc + 8][li] = A[(long)(cb + lc + 8) * C + i0 + li];
    sb[lc][li]     = B[(long)(cb + lc) * C + j0 + li];
    sb[lc + 8][li] = B[(long)(cb + lc + 8) * C + j0 + li];
    __syncthreads();
#pragma unroll
    for (int c = 0; c < 16; ++c){
      const float a0 = sa[c][ti * 2], a1 = sa[c][ti * 2 + 1];
      const float b0 = sb[c][tj * 2], b1 = sb[c][tj * 2 + 1];
      acc[0][0] = fmaf(a0, b0, acc[0][0]); acc[0][1] = fmaf(a0, b1, acc[0][1]);
      acc[1][0] = fmaf(a1, b0, acc[1][0]); acc[1][1] = fmaf(a1, b1, acc[1][1]);
    }
    __syncthreads();
  }
#pragma unroll
  for (int r = 0; r < 2; ++r)
#pragma unroll
    for (int s = 0; s < 2; ++s)
      C2[(long)(i0 + ti * 2 + r) * C + j0 + tj * 2 + s] = acc[r][s] * alpha;
}

__global__ __launch_bounds__(256) void k_wtv(const float* __restrict__ W, const float* __restrict__ b,
                                             float* __restrict__ u){
  __shared__ float sb2[C];
  const int t = threadIdx.x;
  sb2[t] = b[t]; sb2[t + 256] = b[t + 256];
  __syncthreads();
  const int e = blockIdx.x * 256 + t;
  float acc = 0.f;
  for (int c = 0; c < C; ++c) acc = fmaf(W[(long)c * C + e], sb2[c], acc);
  u[e] = acc;
}

__global__ void k_dot2(const float* __restrict__ a1, const float* __restrict__ b1,
                       const float* __restrict__ a2, const float* __restrict__ b2,
                       float* __restrict__ c0m2, float* __restrict__ c0s4){
  const int t = threadIdx.x;
  float s1 = 0.f, s2 = 0.f;
  for (int i = t; i < C; i += 256){ s1 += a1[i] * b1[i]; s2 += a2[i] * b2[i]; }
  __shared__ float sh1[4], sh2[4];
  s1 = wredSum(s1); s2 = wredSum(s2);
  if ((t & 63) == 0){ sh1[t >> 6] = s1; sh2[t >> 6] = s2; }
  __syncthreads();
  if (t == 0){
    float d1 = sh1[0] + sh1[1] + sh1[2] + sh1[3];
    float d2 = sh2[0] + sh2[1] + sh2[2] + sh2[3];
    c0m2[0] = d1; c0m2[1] = d1;
    c0s4[0] = d2; c0s4[1] = d2; c0s4[2] = d2; c0s4[3] = d2;
  }
}

__global__ __launch_bounds__(256) void k_pixvec(const __bf16* __restrict__ X, const float* __restrict__ u,
                                                float* __restrict__ out){
  const int z = blockIdx.y;
  const int wv = threadIdx.x >> 6, lane = threadIdx.x & 63;
  const int n = blockIdx.x * 4 + wv;
  float acc = 0.f;
  for (int d = lane; d < C; d += 64) acc += (float)X[(long)z * NC + (long)n * C + d] * u[d];
  acc = wredSum(acc);
  if (lane == 0) out[(long)z * N + n] = acc;
}

// ======================= prep / stats =======================
__global__ __launch_bounds__(256) void k_stats(const float* __restrict__ x, const float* __restrict__ y,
                                               float* __restrict__ meanv, float* __restrict__ invs){
  const int bid = blockIdx.x;
  const int t = bid >> 9, c = bid & 511;
  const float* src = (t < 2 ? x : y) + (long)(t & 1) * CN + (long)c * N;
  const int tid = threadIdx.x;
  float s1 = 0.f, s2 = 0.f;
  for (int i = tid; i < N; i += 256){ float v = src[i]; s1 += v; s2 += v * v; }
  __shared__ float sh1[4], sh2[4];
  s1 = wredSum(s1); s2 = wredSum(s2);
  if ((tid & 63) == 0){ sh1[tid >> 6] = s1; sh2[tid >> 6] = s2; }
  __syncthreads();
  if (tid == 0){
    float m = (sh1[0] + sh1[1] + sh1[2] + sh1[3]) * (1.f / (float)N);
    float ex2 = (sh2[0] + sh2[1] + sh2[2] + sh2[3]) * (1.f / (float)N);
    float var = ex2 - m * m;
    meanv[t * C + c] = m;
    invs[t * C + c] = rsqrtf((var > 0.f ? var : 0.f) + EPSC);
  }
}

__global__ __launch_bounds__(256) void k_prep(const float* __restrict__ src,
                                              const float* __restrict__ meanv, const float* __restrict__ invs, int toff,
                                              __bf16* __restrict__ adH,
                                              __bf16* __restrict__ fcH, __bf16* __restrict__ fcL,
                                              __bf16* __restrict__ ccH, __bf16* __restrict__ ccL,
                                              __bf16* __restrict__ rwH){
  __shared__ float tile[64][65];
  const int z = blockIdx.z;
  const int n0 = blockIdx.x * 64;
  const int c0 = blockIdx.y * 64;
  const int tid = threadIdx.x;
  const int tx = tid & 63, ty = tid >> 6;
  const int tgt = toff + z;
#pragma unroll
  for (int it = 0; it < 16; ++it){
    const int cc = it * 4 + ty;
    const float v = src[(long)z * CN + (long)(c0 + cc) * N + n0 + tx];
    tile[cc][tx] = v;
    const float cen = v - meanv[tgt * C + c0 + cc];
    splitw(cen, ccH, ccL, (long)tgt * CN + (long)(c0 + cc) * N + n0 + tx);
  }
  __syncthreads();
  const float m = meanv[tgt * C + c0 + tx];
  const float r = invs[tgt * C + c0 + tx];
#pragma unroll
  for (int it = 0; it < 16; ++it){
    const int p = it * 4 + ty;
    const float v = tile[tx][p];
    const float cen = v - m;
    const long o = (long)z * NC + (long)(n0 + p) * C + c0 + tx;
    adH[o] = (__bf16)(cen * r);
    splitw(cen, fcH, fcL, (long)tgt * NC + (long)(n0 + p) * C + c0 + tx);
    if (rwH) rwH[o] = (__bf16)v;
  }
}

__global__ __launch_bounds__(256) void k_wcvt(const float* __restrict__ s, __bf16* __restrict__ h,
                                              __bf16* __restrict__ l, int n){
  int i = blockIdx.x * 256 + threadIdx.x;
  if (i < n) splitw(s[i], h, l, i);
}
__global__ __launch_bounds__(256) void k_wcvt_h(const float* __restrict__ s, __bf16* __restrict__ h, int n){
  int i = blockIdx.x * 256 + threadIdx.x;
  if (i < n) h[i] = (__bf16)s[i];
}

// ======================= cov diag / power iteration / NS init =======================
__global__ void k_diag(float* __restrict__ cov){
  const int z = blockIdx.x, t = threadIdx.x;
  for (int i = t; i < C; i += 256) cov[(long)z * CC + (long)i * C + i] += 2.f * EPSC;
}

// 4 power iterations; under-estimating lambda by <=10% is safe (NS needs lambda/t < 2).
__global__ __launch_bounds__(256) void k_powit(const float* __restrict__ cov,
                                               float* __restrict__ invt, float* __restrict__ invsqt){
  __shared__ float v[C], red[4];
  const int z = blockIdx.x, t = threadIdx.x;
  const float* A = cov + (long)z * CC;
  const int j0 = t, j1 = t + 256;
  v[j0] = 1.f + 0.0003f * (float)j0;
  v[j1] = 1.f + 0.0003f * (float)j1;
  __syncthreads();
  float lam = 1.f;
  for (int it = 0; it < 4; ++it){
    float w0a = 0.f, w0b = 0.f, w1a = 0.f, w1b = 0.f;
#pragma unroll 8
    for (int c = 0; c < C; c += 2){
      const float vc0 = v[c], vc1 = v[c + 1];
      w0a = fmaf(A[(long)c * C + j0], vc0, w0a);
      w1a = fmaf(A[(long)c * C + j1], vc0, w1a);
      w0b = fmaf(A[(long)(c + 1) * C + j0], vc1, w0b);
      w1b = fmaf(A[(long)(c + 1) * C + j1], vc1, w1b);
    }
    const float w0 = w0a + w0b, w1 = w1a + w1b;
    float s = w0 * w0 + w1 * w1;
    s = wredSum(s);
    if ((t & 63) == 0) red[t >> 6] = s;
    __syncthreads();
    const float nrm = sqrtf(red[0] + red[1] + red[2] + red[3]);
    lam = nrm;
    const float inv = 1.f / nrm;
    v[j0] = w0 * inv;
    v[j1] = w1 * inv;
    __syncthreads();
  }
  if (t == 0){
    const float tt = 1.02f * lam;
    invt[z] = 1.f / tt;
    invsqt[z] = rsqrtf(tt);
  }
}

__global__ __launch_bounds__(256) void k_ns_init(const float* __restrict__ cov, const float* __restrict__ invt,
                                                 __bf16* __restrict__ h, __bf16* __restrict__ l,
                                                 __bf16* __restrict__ cph, __bf16* __restrict__ cpl){
  const int r = blockIdx.x, z = blockIdx.y;
  const long base = (long)z * CC + (long)r * C;
  const float it = invt[z];
  for (int i = threadIdx.x; i < C; i += 256){
    const float v = cov[base + i] * it;
    splitw(v, h, l, base + i);
    splitw(v, cph, cpl, base + i);
    h[4 * CC + base + i] = (__bf16)((i == r) ? 1.f : 0.f);
    l[4 * CC + base + i] = (__bf16)0.f;
  }
}

// ======================= self-path softmax aux (epilogue-partial based) =======================
// merge 32 per-block (m,s) partials per row -> rm, rsc=1/S
__global__ __launch_bounds__(256) void k_prowmerge(const float* __restrict__ Pm, const float* __restrict__ Ps,
                                                   float* __restrict__ rm, float* __restrict__ rsc){
  const int row = blockIdx.x * 256 + threadIdx.x;
  float m = -3.4e38f, s = 0.f;
#pragma unroll 4
  for (int p = 0; p < 32; ++p){
    const float mp = Pm[(long)p * N + row];
    const float sp = Ps[(long)p * N + row];
    const float nm = fmaxf(m, mp);
    s = s * __expf(m - nm) + sp * __expf(mp - nm);
    m = nm;
  }
  rm[row] = m;
  rsc[row] = 1.f / s;
}

// single E read: column partial accumulation (128 rows per y-block)
__global__ __launch_bounds__(256) void k_colaccum(const float* __restrict__ E, const float* __restrict__ rowmax,
                                                  const float* __restrict__ rowscale, float* __restrict__ partials){
  const int j = (blockIdx.x * 256 + threadIdx.x) * 4;
  const int r0 = blockIdx.y * 128;
  float4 acc = {0.f, 0.f, 0.f, 0.f};
  for (int r2 = r0; r2 < r0 + 128; ++r2){
    const float4 e = *reinterpret_cast<const float4*>(E + (long)r2 * N + j);
    const float rmv = rowmax[r2], rsv = rowscale[r2];
    acc.x += __expf(e.x - rmv) * rsv;
    acc.y += __expf(e.y - rmv) * rsv;
    acc.z += __expf(e.z - rmv) * rsv;
    acc.w += __expf(e.w - rmv) * rsv;
  }
  *reinterpret_cast<float4*>(partials + (long)blockIdx.y * N + j) = acc;
}

__global__ __launch_bounds__(256) void k_colreduce(const float* __restrict__ partials, float* __restrict__ att){
  const int j = blockIdx.x * 256 + threadIdx.x;
  float s = 0.f;
#pragma unroll 4
  for (int p = 0; p < 32; ++p) s += partials[(long)p * N + j];
  att[j] = s * (1.f / (float)N);
}

// ======================= main-path masked row stats (bf16 E), single-pass online =======================
__global__ __launch_bounds__(256) void k_rowstats1(
    const __bf16* __restrict__ E, const float* __restrict__ mx, const float* __restrict__ my,
    float* __restrict__ rowmax, float* __restrict__ rowscale)
{
  const int zz = blockIdx.y;
  const int r0 = blockIdx.x * 16;
  const int tid = threadIdx.x;
  const int rr = tid >> 4;
  const int l16 = tid & 15;
  const int row = r0 + rr;
  const __bf16* pe = E + (long)zz * NN + (long)row * N;
  const float target = mx[row];
  float m = -3.4e38f, s = 0.f, sm = 0.f;
  for (int i = l16 * 8; i < N; i += 128){
    const bf16x8 ev = *(const bf16x8*)(pe + i);
    const float4 w0 = *(const float4*)(my + i);
    const float4 w1 = *(const float4*)(my + i + 4);
    float e[8];
#pragma unroll
    for (int k = 0; k < 8; ++k) e[k] = (float)ev[k];
    float mv = fmaxf(fmaxf(fmaxf(e[0], e[1]), fmaxf(e[2], e[3])),
                     fmaxf(fmaxf(e[4], e[5]), fmaxf(e[6], e[7])));
    if (mv > m){ const float sc = __expf(m - mv); s *= sc; sm *= sc; m = mv; }
    float x0 = __expf(e[0] - m), x1 = __expf(e[1] - m), x2 = __expf(e[2] - m), x3 = __expf(e[3] - m);
    float x4 = __expf(e[4] - m), x5 = __expf(e[5] - m), x6 = __expf(e[6] - m), x7 = __expf(e[7] - m);
    s += ((x0 + x1) + (x2 + x3)) + ((x4 + x5) + (x6 + x7));
    if (w0.x == target) sm += x0;
    if (w0.y == target) sm += x1;
    if (w0.z == target) sm += x2;
    if (w0.w == target) sm += x3;
    if (w1.x == target) sm += x4;
    if (w1.y == target) sm += x5;
    if (w1.z == target) sm += x6;
    if (w1.w == target) sm += x7;
  }
#pragma unroll
  for (int o = 8; o >= 1; o >>= 1){
    const float mo = __shfl_xor(m, o, 64);
    const float so = __shfl_xor(s, o, 64);
    const float smo = __shfl_xor(sm, o, 64);
    const float nm = fmaxf(m, mo);
    const float sc0 = __expf(m - nm), sc1 = __expf(mo - nm);
    s = s * sc0 + so * sc1;
    sm = sm * sc0 + smo * sc1;
    m = nm;
  }
  if (l16 == 0){
    float l1 = sm / s;
    if (l1 < 1e-12f) l1 = 1e-12f;
    rowscale[(long)zz * N + row] = 1.f / (s * l1);
    rowmax[(long)zz * N + row] = m;
  }
}

// ======================= mask (radix select) =======================
__global__ __launch_bounds__(256) void k_radix(const float* __restrict__ a, float* __restrict__ thr){
  __shared__ unsigned int vals[N];
  __shared__ float shc[4];
  __shared__ unsigned int p_sh;
  __shared__ int k_sh;
  const float* pa = a + (long)blockIdx.x * N;
  const int tid = threadIdx.x;
  for (int i = tid; i < N; i += 256) vals[i] = __float_as_uint(pa[i]);
  if (tid == 0){ p_sh = 0u; k_sh = KSEL; }
  __syncthreads();
  for (int b = 31; b >= 0; --b){
    const unsigned int bit = 1u << b;
    const unsigned int above = (b == 31) ? 0u : ~((bit << 1) - 1u);
    const unsigned int p = p_sh;
    int cnt = 0;
    for (int i = tid; i < N; i += 256){
      unsigned int v = vals[i];
      if ((v & above) == p && (v & bit)) cnt++;
    }
    float cf = wredSum((float)cnt);
    if ((tid & 63) == 0) shc[tid >> 6] = cf;
    __syncthreads();
    if (tid == 0){
      int c1 = (int)(shc[0] + shc[1] + shc[2] + shc[3] + 0.5f);
      if (k_sh <= c1) p_sh = p | bit;
      else k_sh -= c1;
    }
    __syncthreads();
  }
  if (tid == 0) thr[blockIdx.x] = __uint_as_float(p_sh);
}

__global__ __launch_bounds__(256) void k_mask(const float* __restrict__ ax, const float* __restrict__ ay,
                                              const float* __restrict__ thr, float* __restrict__ mx,
                                              float* __restrict__ my){
  int j = blockIdx.x * 256 + threadIdx.x;
  mx[j] = (ax[j] >= thr[0] && ax[N + j] >= thr[1]) ? 1.f : 0.f;
  my[j] = (ay[j] >= thr[2] && ay[N + j] >= thr[3]) ? 1.f : 0.f;
}

// ======================= host =======================
extern "C" void kernel_launch(void* const* d_in, const int* in_sizes, int n_in,
                              void* d_out, int out_size, void* d_ws, size_t ws_size,
                              hipStream_t stream)
{
  const float* x     = (const float*)d_in[0];
  const float* y     = (const float*)d_in[1];
  const float* f_w   = (const float*)d_in[2];
  const float* f_b   = (const float*)d_in[3];
  const float* g_w   = (const float*)d_in[4];
  const float* g_b   = (const float*)d_in[5];
  const float* saf_w = (const float*)d_in[6];
  const float* saf_b = (const float*)d_in[7];
  const float* sag_w = (const float*)d_in[8];
  const float* sag_b = (const float*)d_in[9];
  const float* h_w   = (const float*)d_in[10];
  const float* h_b   = (const float*)d_in[11];
  const float* ow    = (const float*)d_in[12];
  const float* ob    = (const float*)d_in[13];

  const size_t MBy = 1ull << 20;
  char* base = (char*)d_ws;
  if (ws_size < 206 * MBy) return;
  auto F  = [&](size_t off){ return (float*)(base + off); };
  auto Bp = [&](size_t off){ return (__bf16*)(base + off); };

  float *E0 = F(0);
  __bf16 *Ebf = Bp(0);
  __bf16 *ccH = Bp(0), *ccL = Bp(16*MBy);
  float  *covb = F(32*MBy);
  __bf16 *zpolH = Bp(36*MBy), *zpolL = Bp(38*MBy);
  __bf16 *covPH = Bp(40*MBy), *covPL = Bp(42*MBy);
  float  *KsTf = F(44*MBy), *K2tf = F(45*MBy);
  __bf16 *KsTH = Bp(46*MBy), *KsTL = Bp(46*MBy + 512*1024);
  __bf16 *K2tH = Bp(47*MBy), *hwH = Bp(47*MBy + 512*1024);
  __bf16 *tpH = Bp(48*MBy), *tpL = Bp(50*MBy);
  __bf16 *xaH = Bp(64*MBy);
  __bf16 *xzH = Bp(64*MBy), *xzL = Bp(80*MBy);
  __bf16 *ypmH = Bp(96*MBy);
  __bf16 *AsH = Bp(96*MBy), *AsL = Bp(112*MBy);
  __bf16 *fcH = Bp(128*MBy), *fcL = Bp(144*MBy);
  __bf16 *resH = Bp(128*MBy);
  __bf16 *nsAh = Bp(160*MBy), *nsAl = Bp(164*MBy);
  __bf16 *nsBh = Bp(168*MBy), *nsBl = Bp(172*MBy);
  __bf16 *A2H = Bp(176*MBy);
  __bf16 *yaH = Bp(184*MBy);
  __bf16 *hH  = Bp(192*MBy);
  __bf16 *owH = Bp(200*MBy);
  size_t so = 200 * MBy + 512 * 1024;
  auto SF = [&](size_t bytes){ float* p = F(so); so += bytes; return p; };
  float *meanv = SF(8*1024), *invs = SF(8*1024);
  float *rm = SF(32*1024), *rsc = SF(32*1024);
  float *mxv = SF(16*1024), *myv = SF(16*1024);
  float *rvec2 = SF(32*1024), *cvec2 = SF(32*1024);
  float *rvS = SF(64*1024), *cvS = SF(64*1024);
  float *u1m = SF(2*1024), *u2m = SF(2*1024), *u1s = SF(2*1024), *u2s = SF(2*1024);
  float *c0m2 = SF(64), *c0s4 = SF(64), *thr = SF(64);
  float *invt = SF(64), *invsqt = SF(64);
  float *partials = F(201*MBy);                      // [32][N]
  float *Pm = F(201*MBy + 512*1024);                 // [32][N]
  float *Ps = F(201*MBy + 1024*1024);                // [32][N]

  float* outm = (float*)d_out;
  float* attx = outm + B2 * CN;
  float* atty = attx + (long)B2 * N;

  // 1) stats + prep
  k_stats<<<dim3(4 * C), dim3(256), 0, stream>>>(x, y, meanv, invs);
  k_prep<<<dim3(64, 8, 2), dim3(256), 0, stream>>>(x, meanv, invs, 0, xaH, fcH, fcL, ccH, ccL, nullptr);
  k_prep<<<dim3(64, 8, 2), dim3(256), 0, stream>>>(y, meanv, invs, 2, yaH, fcH, fcL, ccH, ccL, ypmH);

  // 2) weight products & conversions
  k_wtw<<<dim3(16, 16), dim3(256), 0, stream>>>(sag_w, saf_w, KsTf, 1.f);
  k_wtw<<<dim3(16, 16), dim3(256), 0, stream>>>(g_w, f_w, K2tf, 1.f);
  {
    const int nb = (int)(CC / 256);
    k_wcvt<<<nb, 256, 0, stream>>>(KsTf, KsTH, KsTL, (int)CC);
    k_wcvt_h<<<nb, 256, 0, stream>>>(K2tf, K2tH, (int)CC);
    k_wcvt_h<<<nb, 256, 0, stream>>>(h_w, hwH, (int)CC);
    k_wcvt_h<<<nb, 256, 0, stream>>>(ow, owH, (int)CC);
  }
  k_wtv<<<dim3(2), dim3(256), 0, stream>>>(g_w, f_b, u1m);
  k_wtv<<<dim3(2), dim3(256), 0, stream>>>(f_w, g_b, u2m);
  k_wtv<<<dim3(2), dim3(256), 0, stream>>>(sag_w, saf_b, u1s);
  k_wtv<<<dim3(2), dim3(256), 0, stream>>>(saf_w, sag_b, u2s);
  k_dot2<<<dim3(1), dim3(256), 0, stream>>>(f_b, g_b, saf_b, sag_b, c0m2, c0s4);
  k_pixvec<<<dim3(N / 4, 2), dim3(256), 0, stream>>>(xaH, u2m, rvec2);
  k_pixvec<<<dim3(N / 4, 2), dim3(256), 0, stream>>>(yaH, u1m, cvec2);

  // 3) cov + 2eps*I + power-iteration lambda_max
  k_mm64<0,0,0><<<dim3(8, 8, 4), dim3(256), 0, stream>>>(
      ccH, ccL, ccH, ccL, nullptr, nullptr, covb, nullptr, nullptr, C, N, CN, CN, CC, 1.f / (float)(N - 1));
  k_diag<<<dim3(4), dim3(256), 0, stream>>>(covb);
  k_powit<<<dim3(4), dim3(256), 0, stream>>>(covb, invt, invsqt);

  // 4) A2 = xa . K2^T, h conv
  k_mm<1,0,2,0><<<dim3(32, 4, 2), dim3(256), 0, stream>>>(xaH, nullptr, K2tH, nullptr, nullptr, A2H, nullptr,
      C, C, NC, 0, NC, 1.f, nullptr, nullptr, 0, nullptr, 0, nullptr, nullptr, 0, nullptr, nullptr);
  k_mm<1,0,2,0><<<dim3(4, 32, 2), dim3(256), 0, stream>>>(hwH, nullptr, ypmH, nullptr, nullptr, hH, nullptr,
      N, C, 0, NC, CN, 1.f, nullptr, h_b, 0, nullptr, 0, nullptr, nullptr, 0, nullptr, nullptr);

  // 5) Newton-Schulz (4 iters) + split-bf16 polish
  k_ns_init<<<dim3(C, 4), dim3(256), 0, stream>>>(covb, invt, nsAh, nsAl, covPH, covPL);
  __bf16 *cah = nsAh, *cal = nsAl, *cbh = nsBh, *cbl = nsBl;
  for (int it = 0; it < NS_ITERS; ++it){
    k_mm64<1,1,0><<<dim3(8, 8, 4), dim3(256), 0, stream>>>(
        cah + 4*CC, cal + 4*CC, cah, cal, nullptr, nullptr, nullptr, tpH, tpL, C, C, CC, CC, CC, 1.f);
    k_mm64<0,1,1><<<dim3(8, 8, 8), dim3(256), 0, stream>>>(
        cah, cal, nullptr, nullptr, tpH, tpL, nullptr, cbh, cbl, C, C, CC, CC, CC, 1.f);
    __bf16* t;
    t = cah; cah = cbh; cbh = t;
    t = cal; cal = cbl; cbl = t;
  }
  k_mm64<0,1,0><<<dim3(8, 8, 4), dim3(256), 0, stream>>>(
      cah + 4*CC, cal + 4*CC, cah + 4*CC, cal + 4*CC, nullptr, nullptr, nullptr, tpH, tpL, C, C, CC, CC, CC, 1.f);
  k_mm64<1,1,0><<<dim3(8, 8, 4), dim3(256), 0, stream>>>(
      covPH, covPL, tpH, tpL, nullptr, nullptr, nullptr, cbh, cbl, C, C, CC, CC, CC, 1.f);
  k_mm64<0,1,0><<<dim3(8, 8, 4), dim3(256), 0, stream>>>(
      cah + 4*CC, cal + 4*CC, cbh, cbl, nullptr, nullptr, nullptr, zpolH, zpolL, C, C, CC, CC, CC, 1.f);

  // 6) zca apply: xz = invsqt * fc . Z
  k_mm<3,0,1,0><<<dim3(32, 4, 4), dim3(256), 0, stream>>>(fcH, fcL, zpolH, zpolL, nullptr, xzH, xzL,
      C, C, NC, CC, NC, 1.f, invsqt, nullptr, 0, nullptr, 0, nullptr, nullptr, 0, nullptr, nullptr);

  // 6.5) self bias vecs + As = xz . Ks^T
  k_pixvec<<<dim3(N / 4, 4), dim3(256), 0, stream>>>(xzH, u2s, rvS);
  k_pixvec<<<dim3(N / 4, 4), dim3(256), 0, stream>>>(xzH, u1s, cvS);
  k_mm<3,0,1,0><<<dim3(32, 4, 4), dim3(256), 0, stream>>>(xzH, xzL, KsTH, KsTL, nullptr, AsH, AsL,
      C, C, NC, 0, NC, 1.f, nullptr, nullptr, 0, nullptr, 0, nullptr, nullptr, 0, nullptr, nullptr);

  // 7) self-attention energies -> atten (fp32 E; row-stats fused into GEMM epilogue)
  for (int z = 0; z < 4; ++z){
    k_mm<3,0,0,1><<<dim3(32, 32, 1), dim3(256), 0, stream>>>(AsH + (long)z*NC, AsL + (long)z*NC,
        xzH + (long)z*NC, xzL + (long)z*NC, E0, nullptr, nullptr,
        N, C, 0, 0, 0, 1.f, nullptr, rvS + (long)z*N, 0, cvS + (long)z*N, 0, c0s4, nullptr, 0, Pm, Ps);
    k_prowmerge<<<dim3(16), dim3(256), 0, stream>>>(Pm, Ps, rm, rsc);
    k_colaccum<<<dim3(4, 32), dim3(256), 0, stream>>>(E0, rm, rsc, partials);
    k_colreduce<<<dim3(16), dim3(256), 0, stream>>>(partials, (z < 2 ? attx : atty) + (long)(z & 1) * N);
  }

  // 8) masks
  k_radix<<<dim3(2), dim3(256), 0, stream>>>(attx, thr);
  k_radix<<<dim3(2), dim3(256), 0, stream>>>(atty, thr + 2);
  k_mask<<<dim3(16), dim3(256), 0, stream>>>(attx, atty, thr, mxv, myv);

  // 9) main path: energy -> bf16 E; online masked rowstats; fused corr+PV; out conv
  k_mm<1,0,2,0><<<dim3(32, 32, 2), dim3(256), 0, stream>>>(A2H, nullptr, yaH, nullptr, nullptr, Ebf, nullptr,
      N, C, NC, NC, NN, 1.f, nullptr, rvec2, N, cvec2, N, c0m2, nullptr, 0, nullptr, nullptr);
  k_rowstats1<<<dim3(N / 16, 2), dim3(256), 0, stream>>>(Ebf, mxv, myv, rm, rsc);
  k_pv<<<dim3(64, 4, 2), dim3(256), 0, stream>>>(Ebf, hH, rm, rsc, mxv, myv, resH);
  k_mm<1,0,0,0><<<dim3(4, 32, 2), dim3(256), 0, stream>>>(owH, nullptr, resH, nullptr, outm, nullptr, nullptr,
      N, C, 0, NC, CN, 1.f, nullptr, ob, 0, nullptr, 0, nullptr, x, CN, nullptr, nullptr);
}